// Round 1
// baseline (8307.565 us; speedup 1.0000x reference)
//
#include <hip/hip_runtime.h>

#define PIX 25088
#define NB 8
#define HH 56
#define WW 56
#define CC 256
#define P2 49
#define TOPKN 4
#define NHEADS 8
#define CD 32

__device__ __forceinline__ float gelu_f(float v){
    return 0.5f*v*(1.0f+erff(v*0.70710678118654752f));
}
__device__ __forceinline__ float sigmoid_f(float v){
    return 1.0f/(1.0f+__expf(-v));
}

// ---------------- NCHW -> NHWC transpose (tiled) ----------------
__global__ __launch_bounds__(1024) void nchw_to_nhwc(const float* __restrict__ in, float* __restrict__ out){
    __shared__ float t[32][33];
    int pb = blockIdx.x;            // n * 98 + p-tile
    int n  = pb / 98;
    int p0 = (pb % 98) * 32;
    int c0 = blockIdx.y * 32;
    int tx = threadIdx.x, ty = threadIdx.y;
    t[ty][tx] = in[(size_t)(n*CC + c0+ty)*3136 + p0 + tx];
    __syncthreads();
    out[(size_t)(n*3136 + p0 + ty)*CC + c0 + tx] = t[tx][ty];
}

// ---------------- LayerNorm over C=256 ----------------
__global__ __launch_bounds__(256) void ln_kernel(const float* __restrict__ x, const float* __restrict__ w,
                                                 const float* __restrict__ b, float* __restrict__ y){
    int row = blockIdx.x, tid = threadIdx.x;
    __shared__ float red[256];
    float v = x[(size_t)row*CC + tid];
    red[tid] = v; __syncthreads();
    for(int s=128;s>0;s>>=1){ if(tid<s) red[tid]+=red[tid+s]; __syncthreads(); }
    float mu = red[0]*(1.0f/CC);
    __syncthreads();
    float d = v - mu;
    red[tid] = d*d; __syncthreads();
    for(int s=128;s>0;s>>=1){ if(tid<s) red[tid]+=red[tid+s]; __syncthreads(); }
    float var = red[0]*(1.0f/CC);
    y[(size_t)row*CC+tid] = d*rsqrtf(var+1e-6f)*w[tid]+b[tid];
}

// ---------------- f32 tiled GEMM 64x64x16, 4x4 per thread ----------------
// epi: 0 none, 1 gelu(exact), 2 sigmoid.  res: optional additive residual.
// transB: 0 -> B is [K,N] row-major; 1 -> B is [N,K] row-major.
__global__ __launch_bounds__(256) void gemm_kernel(
    const float* __restrict__ A, const float* __restrict__ B,
    const float* __restrict__ bias, const float* __restrict__ res,
    float* __restrict__ C, int M, int N, int K, int transB, int epi)
{
    __shared__ float As[16][64];
    __shared__ float Bs[16][64];
    int tid = threadIdx.x;
    int tx = tid & 15, ty = tid >> 4;
    int row0 = blockIdx.y*64, col0 = blockIdx.x*64;
    float acc[4][4] = {};
    for(int k0=0;k0<K;k0+=16){
        {   // A tile: 64x16, one float4 per thread
            int r = tid >> 2, kq = (tid & 3) << 2;
            const float4 a4 = *reinterpret_cast<const float4*>(&A[(size_t)(row0+r)*K + k0 + kq]);
            As[kq+0][r]=a4.x; As[kq+1][r]=a4.y; As[kq+2][r]=a4.z; As[kq+3][r]=a4.w;
        }
        if(!transB){
            int kk = tid >> 4, cq = (tid & 15) << 2;
            const float4 b4 = *reinterpret_cast<const float4*>(&B[(size_t)(k0+kk)*N + col0 + cq]);
            *reinterpret_cast<float4*>(&Bs[kk][cq]) = b4;
        } else {
            int c = tid >> 2, kq = (tid & 3) << 2;
            const float4 b4 = *reinterpret_cast<const float4*>(&B[(size_t)(col0+c)*K + k0 + kq]);
            Bs[kq+0][c]=b4.x; Bs[kq+1][c]=b4.y; Bs[kq+2][c]=b4.z; Bs[kq+3][c]=b4.w;
        }
        __syncthreads();
        #pragma unroll
        for(int kk=0;kk<16;kk++){
            float4 a  = *reinterpret_cast<const float4*>(&As[kk][ty<<2]);
            float4 bv = *reinterpret_cast<const float4*>(&Bs[kk][tx<<2]);
            float av[4]={a.x,a.y,a.z,a.w}, bb[4]={bv.x,bv.y,bv.z,bv.w};
            #pragma unroll
            for(int i=0;i<4;i++)
                #pragma unroll
                for(int j=0;j<4;j++)
                    acc[i][j] += av[i]*bb[j];
        }
        __syncthreads();
    }
    #pragma unroll
    for(int i=0;i<4;i++){
        int r = row0 + (ty<<2) + i;
        #pragma unroll
        for(int j=0;j<4;j++){
            int c = col0 + (tx<<2) + j;
            float v = acc[i][j] + bias[c];
            if(epi==1) v = gelu_f(v);
            else if(epi==2) v = sigmoid_f(v);
            if(res) v += res[(size_t)r*N + c];
            C[(size_t)r*N + c] = v;
        }
    }
}

// ---------------- region means of q and k ----------------
__global__ __launch_bounds__(256) void winmean_kernel(const float* __restrict__ qkv,
                                                      float* __restrict__ qwin, float* __restrict__ kwin){
    int b = blockIdx.x;      // n*49 + p
    int n = b / P2, p = b % P2;
    int c = threadIdx.x;
    int hb = (p/7)*8, wb = (p%7)*8;
    float sq=0.f, sk=0.f;
    for(int pixi=0;pixi<64;pixi++){
        int h = hb + (pixi>>3), w = wb + (pixi&7);
        const float* row = &qkv[((size_t)(n*HH+h)*WW + w)*768];
        sq += row[c];
        sk += row[256+c];
    }
    qwin[(size_t)b*CC+c] = sq*(1.0f/64.0f);
    kwin[(size_t)b*CC+c] = sk*(1.0f/64.0f);
}

// ---------------- routing logits + top-4 ----------------
__global__ __launch_bounds__(64) void route_kernel(const float* __restrict__ qwin, const float* __restrict__ kwin,
                                                   int* __restrict__ idxout){
    int b = blockIdx.x;      // n*49 + p
    int n = b / P2;
    int j = threadIdx.x;
    __shared__ float lg[64];
    float v = -1e30f;
    if(j < P2){
        const float* q = &qwin[(size_t)b*CC];
        const float* k = &kwin[(size_t)(n*P2+j)*CC];
        float s=0.f;
        for(int c=0;c<CC;c++) s += q[c]*k[c];
        v = s*0.0625f;
    }
    lg[j] = v;
    __syncthreads();
    if(j==0){
        for(int t=0;t<TOPKN;t++){
            int best=0; float bv=lg[0];
            for(int u=1;u<P2;u++) if(lg[u]>bv){bv=lg[u];best=u;}
            idxout[b*TOPKN+t]=best;
            lg[best]=-1e30f;
        }
    }
}

// ---------------- attention: one block per (n,p,head), 64 threads = 64 query rows ----------------
__global__ __launch_bounds__(64) void attn_kernel(const float* __restrict__ qkv, const int* __restrict__ idx,
                                                  float* __restrict__ out){
    __shared__ float Kt[256*32];
    __shared__ float Vt[256*32];
    int b = blockIdx.x;
    int m = b & 7; int np = b >> 3;      // np = n*49+p
    int n = np / P2, p = np % P2;
    int tid = threadIdx.x;
    int hb = (p/7)*8, wb = (p%7)*8;
    for(int ii=tid; ii<256*32; ii+=64){
        int j = ii >> 5, c = ii & 31;
        int t = j >> 6, pixi = j & 63;
        int r = idx[np*TOPKN + t];
        int h = (r/7)*8 + (pixi>>3), w = (r%7)*8 + (pixi&7);
        const float* rowp = &qkv[((size_t)(n*HH+h)*WW + w)*768 + m*CD];
        Kt[ii] = rowp[256 + c];
        Vt[ii] = rowp[512 + c];
    }
    __syncthreads();
    int h = hb + (tid>>3), w = wb + (tid&7);
    const float* qrow = &qkv[((size_t)(n*HH+h)*WW + w)*768 + m*CD];
    float q[32];
    #pragma unroll
    for(int c=0;c<32;c++) q[c] = qrow[c]*0.0625f;
    float mx = -1e30f, l = 0.0f;
    float acc[32];
    #pragma unroll
    for(int c=0;c<32;c++) acc[c]=0.0f;
    for(int j=0;j<256;j++){
        float s = 0.f;
        const float* kr = &Kt[j*32];
        #pragma unroll
        for(int c=0;c<32;c++) s += q[c]*kr[c];
        if(s > mx){
            float f = __expf(mx - s);
            l *= f;
            #pragma unroll
            for(int c=0;c<32;c++) acc[c]*=f;
            mx = s;
        }
        float pexp = __expf(s - mx);
        l += pexp;
        const float* vr = &Vt[j*32];
        #pragma unroll
        for(int c=0;c<32;c++) acc[c] += pexp*vr[c];
    }
    float inv = 1.0f/l;
    float* orow = &out[((size_t)(n*HH+h)*WW + w)*CC + m*CD];
    #pragma unroll
    for(int c=0;c<32;c++) orow[c] = acc[c]*inv;
}

// ---------------- LEPE: depthwise 5x5 on v, accumulate into attention output ----------------
__global__ __launch_bounds__(256) void lepe_kernel(const float* __restrict__ qkv, const float* __restrict__ lw,
                                                   const float* __restrict__ lb, float* __restrict__ out){
    int pix = blockIdx.x;   // n*3136 + h*56 + w
    int n = pix / 3136; int rem = pix % 3136; int h = rem/56, w = rem%56;
    int c = threadIdx.x;
    float acc = lb[c];
    const float* wc = &lw[c*25];
    #pragma unroll
    for(int dy=0;dy<5;dy++){
        int y = h + dy - 2;
        if(y<0||y>=HH) continue;
        #pragma unroll
        for(int dx=0;dx<5;dx++){
            int x = w + dx - 2;
            if(x<0||x>=WW) continue;
            acc += qkv[((size_t)(n*HH+y)*WW+x)*768 + 512 + c]*wc[dy*5+dx];
        }
    }
    out[(size_t)pix*CC + c] += acc;
}

// ---------------- global average pool over H,W (NHWC) ----------------
__global__ __launch_bounds__(256) void pool_kernel(const float* __restrict__ x, float* __restrict__ pooled){
    int n = blockIdx.x, c = threadIdx.x;
    float s=0.f;
    for(int p=0;p<3136;p++) s += x[((size_t)n*3136+p)*CC + c];
    pooled[n*CC+c] = s*(1.0f/3136.0f);
}

// ---------------- channel SE (two tiny FCs) ----------------
__global__ __launch_bounds__(256) void cse_kernel(const float* __restrict__ pooled,
                                                  const float* __restrict__ w1, const float* __restrict__ b1,
                                                  const float* __restrict__ w2, const float* __restrict__ b2,
                                                  float* __restrict__ cfac){
    int n = blockIdx.x, t = threadIdx.x;
    __shared__ float c1[16];
    if(t < 16){
        float s = b1[t];
        for(int c=0;c<CC;c++) s += pooled[n*CC+c]*w1[t*CC+c];
        c1[t] = fmaxf(s, 0.0f);
    }
    __syncthreads();
    float s = b2[t];
    #pragma unroll
    for(int j=0;j<16;j++) s += c1[j]*w2[t*16+j];
    cfac[n*CC+t] = sigmoid_f(s);
}

// ---------------- gating: out = y * (cfac + s) ----------------
__global__ __launch_bounds__(256) void gate_kernel(const float* __restrict__ x, const float* __restrict__ s,
                                                   const float* __restrict__ cfac, float* __restrict__ out){
    size_t i = (size_t)blockIdx.x*256 + threadIdx.x;
    int c = threadIdx.x;
    int n = (int)(i / ((size_t)3136*CC));
    out[i] = x[i]*(cfac[n*CC+c] + s[i]);
}

// ---------------- final 3x3 conv, NHWC in -> NCHW out ----------------
__global__ __launch_bounds__(256) void conv3_kernel(const float* __restrict__ in, const float* __restrict__ cw,
                                                    const float* __restrict__ cb, float* __restrict__ out){
    __shared__ float tile[3*10*256];   // [ry][cx][c]
    int bidx = blockIdx.x;
    int wt = bidx % 7; int rem = bidx / 7; int h = rem % HH; int n = rem / HH;
    int w0 = wt*8;
    int tid = threadIdx.x;
    for(int ii=tid; ii<3*10*256; ii+=256){
        int ry = ii / 2560; int r2 = ii % 2560; int cx = r2 >> 8; int c = r2 & 255;
        int y = h - 1 + ry, x = w0 - 1 + cx;
        float v = 0.0f;
        if(y>=0 && y<HH && x>=0 && x<WW) v = in[((size_t)(n*HH+y)*WW+x)*CC + c];
        tile[ii] = v;
    }
    __syncthreads();
    int o = tid;
    float acc[8];
    float bv = cb[o];
    #pragma unroll
    for(int p=0;p<8;p++) acc[p]=bv;
    const float* wrow = &cw[(size_t)o*2304];
    for(int c=0;c<CC;c++){
        #pragma unroll
        for(int ky=0;ky<3;ky++){
            float row10[10];
            #pragma unroll
            for(int cx=0;cx<10;cx++) row10[cx] = tile[(ky*10+cx)*256 + c];
            #pragma unroll
            for(int kx=0;kx<3;kx++){
                float wv = wrow[c*9 + ky*3 + kx];
                #pragma unroll
                for(int p=0;p<8;p++) acc[p] += row10[kx+p]*wv;
            }
        }
    }
    float* obase = &out[((size_t)(n*CC+o)*HH + h)*WW + w0];
    #pragma unroll
    for(int p=0;p<8;p++) obase[p] = acc[p];
}

extern "C" void kernel_launch(void* const* d_in, const int* in_sizes, int n_in,
                              void* d_out, int out_size, void* d_ws, size_t ws_size,
                              hipStream_t stream){
    const float* x_in   = (const float*)d_in[0];
    const float* ln1w   = (const float*)d_in[1];
    const float* ln1b   = (const float*)d_in[2];
    const float* qkvw   = (const float*)d_in[3];
    const float* qkvb   = (const float*)d_in[4];
    const float* lepew  = (const float*)d_in[5];
    const float* lepeb  = (const float*)d_in[6];
    const float* wow    = (const float*)d_in[7];
    const float* wob    = (const float*)d_in[8];
    const float* ln2w   = (const float*)d_in[9];
    const float* ln2b   = (const float*)d_in[10];
    const float* mlp1w  = (const float*)d_in[11];
    const float* mlp1b  = (const float*)d_in[12];
    const float* mlp2w  = (const float*)d_in[13];
    const float* mlp2b  = (const float*)d_in[14];
    const float* cse1w  = (const float*)d_in[15];
    const float* cse1b  = (const float*)d_in[16];
    const float* cse2w  = (const float*)d_in[17];
    const float* cse2b  = (const float*)d_in[18];
    const float* ssew   = (const float*)d_in[19];
    const float* sseb   = (const float*)d_in[20];
    const float* convw  = (const float*)d_in[21];
    const float* convb  = (const float*)d_in[22];
    float* out = (float*)d_out;

    float* ws     = (float*)d_ws;
    float* bufx   = ws;
    float* bufxn  = bufx   + (size_t)PIX*CC;
    float* bufqkv = bufxn  + (size_t)PIX*CC;
    float* buftmp = bufqkv + (size_t)PIX*768;
    float* qwin   = buftmp + (size_t)PIX*CC;
    float* kwin   = qwin + (size_t)NB*P2*CC;
    float* pooled = kwin + (size_t)NB*P2*CC;
    float* cfac   = pooled + NB*CC;
    int*   idxb   = (int*)(cfac + NB*CC);

    nchw_to_nhwc<<<dim3(NB*98, 8), dim3(32,32), 0, stream>>>(x_in, bufx);

    for(int i=0;i<4;i++){
        ln_kernel<<<PIX,256,0,stream>>>(bufx, ln1w+i*CC, ln1b+i*CC, bufxn);
        gemm_kernel<<<dim3(768/64, PIX/64),256,0,stream>>>(bufxn, qkvw+(size_t)i*CC*768, qkvb+i*768,
                                                           nullptr, bufqkv, PIX, 768, CC, 0, 0);
        winmean_kernel<<<NB*P2,256,0,stream>>>(bufqkv, qwin, kwin);
        route_kernel<<<NB*P2,64,0,stream>>>(qwin, kwin, idxb);
        attn_kernel<<<NB*P2*NHEADS,64,0,stream>>>(bufqkv, idxb, buftmp);
        lepe_kernel<<<PIX,256,0,stream>>>(bufqkv, lepew+(size_t)i*CC*25, lepeb+i*CC, buftmp);
        gemm_kernel<<<dim3(CC/64, PIX/64),256,0,stream>>>(buftmp, wow+(size_t)i*CC*CC, wob+i*CC,
                                                          bufx, bufx, PIX, CC, CC, 0, 0);
        ln_kernel<<<PIX,256,0,stream>>>(bufx, ln2w+i*CC, ln2b+i*CC, bufxn);
        for(int hc=0;hc<2;hc++){
            size_t r0 = (size_t)hc*12544;
            gemm_kernel<<<dim3(1024/64, 12544/64),256,0,stream>>>(bufxn+r0*CC, mlp1w+(size_t)i*CC*1024, mlp1b+i*1024,
                                                                  nullptr, bufqkv, 12544, 1024, CC, 0, 1);
            gemm_kernel<<<dim3(CC/64, 12544/64),256,0,stream>>>(bufqkv, mlp2w+(size_t)i*1024*CC, mlp2b+i*CC,
                                                                bufx+r0*CC, bufx+r0*CC, 12544, CC, 1024, 0, 0);
        }
    }

    pool_kernel<<<NB,256,0,stream>>>(bufx, pooled);
    cse_kernel<<<NB,256,0,stream>>>(pooled, cse1w, cse1b, cse2w, cse2b, cfac);
    gemm_kernel<<<dim3(CC/64, PIX/64),256,0,stream>>>(bufx, ssew, sseb, nullptr, buftmp, PIX, CC, CC, 1, 2);
    gate_kernel<<<PIX,256,0,stream>>>(bufx, buftmp, cfac, bufxn);
    conv3_kernel<<<NB*HH*7,256,0,stream>>>(bufxn, convw, convb, out);
}

// Round 6
// 3858.358 us; speedup vs baseline: 2.1531x; 2.1531x over previous
//
#include <hip/hip_runtime.h>

#define PIX 25088
#define NB 8
#define HH 56
#define WW 56
#define CC 256
#define P2 49
#define TOPKN 4

typedef short s16x8 __attribute__((ext_vector_type(8)));
typedef float f32x4 __attribute__((ext_vector_type(4)));

__device__ __forceinline__ float gelu_f(float v){
    return 0.5f*v*(1.0f+erff(v*0.70710678118654752f));
}
__device__ __forceinline__ float sigmoid_f(float v){
    return 1.0f/(1.0f+__expf(-v));
}
__device__ __forceinline__ unsigned short f2bf(float f){
    union { float f; unsigned u; } x; x.f = f;
    unsigned r = x.u + 0x7fffu + ((x.u >> 16) & 1u);
    return (unsigned short)(r >> 16);
}
__device__ __forceinline__ void gload_lds16(const void* g, void* l){
    __builtin_amdgcn_global_load_lds((const __attribute__((address_space(1))) void*)g,
                                     (__attribute__((address_space(3))) void*)l, 16, 0, 0);
}

// ---------------- NCHW -> NHWC transpose (tiled, f32) ----------------
__global__ __launch_bounds__(1024) void nchw_to_nhwc(const float* __restrict__ in, float* __restrict__ out){
    __shared__ float t[32][33];
    int pb = blockIdx.x;            // n * 98 + p-tile
    int n  = pb / 98;
    int p0 = (pb % 98) * 32;
    int c0 = blockIdx.y * 32;
    int tx = threadIdx.x, ty = threadIdx.y;
    t[ty][tx] = in[(size_t)(n*CC + c0+ty)*3136 + p0 + tx];
    __syncthreads();
    out[(size_t)(n*3136 + p0 + ty)*CC + c0 + tx] = t[tx][ty];
}

// ---------------- weight transpose+convert: f32 [K,N] (xLAYERS) -> bf16 [N,K] ----------------
__global__ __launch_bounds__(1024) void wtrans(const float* __restrict__ in, unsigned short* __restrict__ out,
                                               int K, int N){
    int layer = blockIdx.z;
    in  += (size_t)layer*K*N;
    out += (size_t)layer*K*N;
    __shared__ float t[32][33];
    int n0 = blockIdx.x*32, k0 = blockIdx.y*32;
    t[threadIdx.y][threadIdx.x] = in[(size_t)(k0+threadIdx.y)*N + n0 + threadIdx.x];
    __syncthreads();
    out[(size_t)(n0+threadIdx.y)*K + k0 + threadIdx.x] = f2bf(t[threadIdx.x][threadIdx.y]);
}

// ---------------- elementwise f32 -> bf16 ----------------
__global__ __launch_bounds__(256) void tobf16(const float* __restrict__ in, unsigned short* __restrict__ out, int n){
    int i = blockIdx.x*256 + threadIdx.x;
    if(i < n) out[i] = f2bf(in[i]);
}

// ---------------- conv weight reorder: [o][c][3][3] f32 -> [tap][o][c] bf16 ----------------
__global__ __launch_bounds__(256) void convw_reorder(const float* __restrict__ in, unsigned short* __restrict__ out){
    int idx = blockIdx.x*256 + threadIdx.x;      // over 256*256*9
    if(idx >= 256*256*9) return;
    int o = idx / (256*9); int rem = idx % (256*9); int c = rem/9; int t = rem%9;
    out[(size_t)t*65536 + o*256 + c] = f2bf(in[idx]);
}

// ---------------- LayerNorm over C=256, wave per row, bf16 out ----------------
__global__ __launch_bounds__(256) void ln_bf16(const float* __restrict__ x, const float* __restrict__ w,
                                               const float* __restrict__ b, unsigned short* __restrict__ y){
    int row = blockIdx.x*4 + (threadIdx.x >> 6);
    int lane = threadIdx.x & 63;
    const float4 v = *reinterpret_cast<const float4*>(&x[(size_t)row*CC + lane*4]);
    float s = v.x + v.y + v.z + v.w;
    #pragma unroll
    for(int off=32; off>0; off>>=1) s += __shfl_xor(s, off);
    float mu = s*(1.0f/CC);
    float d0=v.x-mu, d1=v.y-mu, d2=v.z-mu, d3=v.w-mu;
    float sq = d0*d0 + d1*d1 + d2*d2 + d3*d3;
    #pragma unroll
    for(int off=32; off>0; off>>=1) sq += __shfl_xor(sq, off);
    float rs = rsqrtf(sq*(1.0f/CC) + 1e-6f);
    const float4 wv = *reinterpret_cast<const float4*>(&w[lane*4]);
    const float4 bv = *reinterpret_cast<const float4*>(&b[lane*4]);
    ushort4 o;
    o.x = f2bf(d0*rs*wv.x + bv.x);
    o.y = f2bf(d1*rs*wv.y + bv.y);
    o.z = f2bf(d2*rs*wv.z + bv.z);
    o.w = f2bf(d3*rs*wv.w + bv.w);
    *reinterpret_cast<ushort4*>(&y[(size_t)row*CC + lane*4]) = o;
}

// ---------------- MFMA GEMM: A bf16 [M,K], Bt bf16 [N,K], 128x128 tile ----------------
// EPI: 0 none, 1 gelu, 2 sigmoid.  HASRES: add res[M,N] f32 after EPI.
// OUTF: write f32 C, OUTB: write bf16 C.
template<int EPI, bool HASRES, bool OUTF, bool OUTB>
__global__ __launch_bounds__(256) void mfma_gemm(
    const unsigned short* __restrict__ A, const unsigned short* __restrict__ Bt,
    const float* __restrict__ bias, const float* __restrict__ res,
    float* __restrict__ Cf, unsigned short* __restrict__ Cb,
    int M, int N, int K)
{
    __shared__ __align__(16) unsigned short As[4096];
    __shared__ __align__(16) unsigned short Bs[4096];
    const int tid = threadIdx.x;
    const int wid = tid >> 6, lane = tid & 63;
    const int row0 = blockIdx.y << 7, col0 = blockIdx.x << 7;
    const int wm = wid >> 1, wn = wid & 1;
    const int li = lane & 15, qq = lane >> 4;

    f32x4 acc[4][4] = {};
    const int nk = K >> 5;
    for(int kt=0; kt<nk; kt++){
        const int k0 = kt << 5;
        #pragma unroll
        for(int i=0;i<2;i++){
            int boff = wid*2048 + i*1024 + (lane<<4);  // byte slot in tile
            int row = boff >> 6;
            int t = (boff >> 4) & 3;
            int q = t ^ ((row >> 1) & 3);
            gload_lds16(A  + (size_t)(row0+row)*K + k0 + q*8, (char*)As + wid*2048 + i*1024);
            gload_lds16(Bt + (size_t)(col0+row)*K + k0 + q*8, (char*)Bs + wid*2048 + i*1024);
        }
        __syncthreads();
        s16x8 af[4], bfr[4];
        #pragma unroll
        for(int mi=0;mi<4;mi++){
            int r = (wm<<6) + (mi<<4) + li;
            af[mi] = *(const s16x8*)((const char*)As + r*64 + ((qq ^ ((r>>1)&3))<<4));
        }
        #pragma unroll
        for(int nj=0;nj<4;nj++){
            int r = (wn<<6) + (nj<<4) + li;
            bfr[nj] = *(const s16x8*)((const char*)Bs + r*64 + ((qq ^ ((r>>1)&3))<<4));
        }
        #pragma unroll
        for(int mi=0;mi<4;mi++)
            #pragma unroll
            for(int nj=0;nj<4;nj++)
                acc[mi][nj] = __builtin_amdgcn_mfma_f32_16x16x32_bf16(af[mi], bfr[nj], acc[mi][nj], 0,0,0);
        __syncthreads();
    }
    #pragma unroll
    for(int mi=0;mi<4;mi++){
        #pragma unroll
        for(int nj=0;nj<4;nj++){
            int col = col0 + (wn<<6) + (nj<<4) + li;
            float bv = bias ? bias[col] : 0.0f;
            #pragma unroll
            for(int rr=0;rr<4;rr++){
                int row = row0 + (wm<<6) + (mi<<4) + (qq<<2) + rr;
                float v = acc[mi][nj][rr] + bv;
                if(EPI==1) v = gelu_f(v);
                if(EPI==2) v = sigmoid_f(v);
                if(HASRES) v += res[(size_t)row*N + col];
                if(OUTF) Cf[(size_t)row*N + col] = v;
                if(OUTB) Cb[(size_t)row*N + col] = f2bf(v);
            }
        }
    }
}

// ---------------- conv 3x3 as 9-tap accumulated MFMA GEMM over padded image ----------------
// P: padded bf16 image base (guard of 64 rows precedes padded row 0). M=27008 rows.
// CBt: [9][256 out][256 in] bf16. Writes NCHW f32 out for valid pixels, + bias.
__global__ __launch_bounds__(256) void conv_gemm(
    const unsigned short* __restrict__ P, const unsigned short* __restrict__ CBt,
    const float* __restrict__ bias, float* __restrict__ out)
{
    __shared__ __align__(16) unsigned short As[4096];
    __shared__ __align__(16) unsigned short Bs[4096];
    const int tid = threadIdx.x;
    const int wid = tid >> 6, lane = tid & 63;
    const int row0 = blockIdx.y << 7, col0 = blockIdx.x << 7;
    const int wm = wid >> 1, wn = wid & 1;
    const int li = lane & 15, qq = lane >> 4;
    const int K = 256;

    f32x4 acc[4][4] = {};
    for(int tap=0; tap<9; tap++){
        int d = ((tap/3)-1)*58 + (tap%3) - 1;
        const unsigned short* A  = P + (size_t)(64 + d)*256;
        const unsigned short* Bt = CBt + (size_t)tap*65536;
        for(int kt=0; kt<8; kt++){
            const int k0 = kt << 5;
            #pragma unroll
            for(int i=0;i<2;i++){
                int boff = wid*2048 + i*1024 + (lane<<4);
                int row = boff >> 6;
                int t = (boff >> 4) & 3;
                int q = t ^ ((row >> 1) & 3);
                gload_lds16(A  + (size_t)(row0+row)*K + k0 + q*8, (char*)As + wid*2048 + i*1024);
                gload_lds16(Bt + (size_t)(col0+row)*K + k0 + q*8, (char*)Bs + wid*2048 + i*1024);
            }
            __syncthreads();
            s16x8 af[4], bfr[4];
            #pragma unroll
            for(int mi=0;mi<4;mi++){
                int r = (wm<<6) + (mi<<4) + li;
                af[mi] = *(const s16x8*)((const char*)As + r*64 + ((qq ^ ((r>>1)&3))<<4));
            }
            #pragma unroll
            for(int nj=0;nj<4;nj++){
                int r = (wn<<6) + (nj<<4) + li;
                bfr[nj] = *(const s16x8*)((const char*)Bs + r*64 + ((qq ^ ((r>>1)&3))<<4));
            }
            #pragma unroll
            for(int mi=0;mi<4;mi++)
                #pragma unroll
                for(int nj=0;nj<4;nj++)
                    acc[mi][nj] = __builtin_amdgcn_mfma_f32_16x16x32_bf16(af[mi], bfr[nj], acc[mi][nj], 0,0,0);
            __syncthreads();
        }
    }
    #pragma unroll
    for(int mi=0;mi<4;mi++){
        #pragma unroll
        for(int nj=0;nj<4;nj++){
            int col = col0 + (wn<<6) + (nj<<4) + li;
            float bv = bias[col];
            #pragma unroll
            for(int rr=0;rr<4;rr++){
                int prow = row0 + (wm<<6) + (mi<<4) + (qq<<2) + rr;
                if(prow < NB*3364){
                    int n = prow / 3364; int rem = prow % 3364;
                    int y = rem / 58, x = rem % 58;
                    if(y>=1 && y<57 && x>=1 && x<57){
                        out[(((size_t)n*CC + col)*HH + (y-1))*WW + (x-1)] = acc[mi][nj][rr] + bv;
                    }
                }
            }
        }
    }
}

// ---------------- region means of q and k ----------------
__global__ __launch_bounds__(256) void winmean_kernel(const float* __restrict__ qkv,
                                                      float* __restrict__ qwin, float* __restrict__ kwin){
    int b = blockIdx.x;      // n*49 + p
    int n = b / P2, p = b % P2;
    int c = threadIdx.x;
    int hb = (p/7)*8, wb = (p%7)*8;
    float sq=0.f, sk=0.f;
    for(int pixi=0;pixi<64;pixi++){
        int h = hb + (pixi>>3), w = wb + (pixi&7);
        const float* row = &qkv[((size_t)(n*HH+h)*WW + w)*768];
        sq += row[c];
        sk += row[256+c];
    }
    qwin[(size_t)b*CC+c] = sq*(1.0f/64.0f);
    kwin[(size_t)b*CC+c] = sk*(1.0f/64.0f);
}

// ---------------- routing logits + top-4 ----------------
__global__ __launch_bounds__(64) void route_kernel(const float* __restrict__ qwin, const float* __restrict__ kwin,
                                                   int* __restrict__ idxout){
    int b = blockIdx.x;      // n*49 + p
    int n = b / P2;
    int j = threadIdx.x;
    __shared__ float lg[64];
    float v = -1e30f;
    if(j < P2){
        const float* q = &qwin[(size_t)b*CC];
        const float* k = &kwin[(size_t)(n*P2+j)*CC];
        float s=0.f;
        for(int c=0;c<CC;c++) s += q[c]*k[c];
        v = s*0.0625f;
    }
    lg[j] = v;
    __syncthreads();
    if(j==0){
        for(int t=0;t<TOPKN;t++){
            int best=0; float bv=lg[0];
            for(int u=1;u<P2;u++) if(lg[u]>bv){bv=lg[u];best=u;}
            idxout[b*TOPKN+t]=best;
            lg[best]=-1e30f;
        }
    }
}

// ---------------- attention: one block per (n,p,head), 64 threads = 64 query rows ----------------
__global__ __launch_bounds__(64) void attn_kernel(const float* __restrict__ qkv, const int* __restrict__ idx,
                                                  float* __restrict__ out){
    __shared__ float Kt[256*32];
    __shared__ float Vt[256*32];
    int b = blockIdx.x;
    int m = b & 7; int np = b >> 3;      // np = n*49+p
    int n = np / P2, p = np % P2;
    int tid = threadIdx.x;
    int hb = (p/7)*8, wb = (p%7)*8;
    for(int ii=tid; ii<256*32; ii+=64){
        int j = ii >> 5, c = ii & 31;
        int t = j >> 6, pixi = j & 63;
        int r = idx[np*TOPKN + t];
        int h = (r/7)*8 + (pixi>>3), w = (r%7)*8 + (pixi&7);
        const float* rowp = &qkv[((size_t)(n*HH+h)*WW + w)*768 + m*32];
        Kt[ii] = rowp[256 + c];
        Vt[ii] = rowp[512 + c];
    }
    __syncthreads();
    int h = hb + (tid>>3), w = wb + (tid&7);
    const float* qrow = &qkv[((size_t)(n*HH+h)*WW + w)*768 + m*32];
    float q[32];
    #pragma unroll
    for(int c=0;c<32;c++) q[c] = qrow[c]*0.0625f;
    float mx = -1e30f, l = 0.0f;
    float acc[32];
    #pragma unroll
    for(int c=0;c<32;c++) acc[c]=0.0f;
    for(int j=0;j<256;j++){
        float s = 0.f;
        const float* kr = &Kt[j*32];
        #pragma unroll
        for(int c=0;c<32;c++) s += q[c]*kr[c];
        if(s > mx){
            float f = __expf(mx - s);
            l *= f;
            #pragma unroll
            for(int c=0;c<32;c++) acc[c]*=f;
            mx = s;
        }
        float pexp = __expf(s - mx);
        l += pexp;
        const float* vr = &Vt[j*32];
        #pragma unroll
        for(int c=0;c<32;c++) acc[c] += pexp*vr[c];
    }
    float inv = 1.0f/l;
    float* orow = &out[((size_t)(n*HH+h)*WW + w)*CC + m*32];
    #pragma unroll
    for(int c=0;c<32;c++) orow[c] = acc[c]*inv;
}

// ---------------- LEPE tiled: attn_out(f32) + dwconv5(v) -> bf16 ----------------
__global__ __launch_bounds__(256) void lepe_kernel(const float* __restrict__ qkv, const float* __restrict__ attn,
                                                   const float* __restrict__ lw, const float* __restrict__ lb,
                                                   unsigned short* __restrict__ outb){
    __shared__ float tile[144][64];     // 12x12 spatial halo x 64 channels
    int tileid = blockIdx.x;            // 0..48
    int cg = blockIdx.y;                // 0..3
    int n = blockIdx.z;
    int hb = (tileid/7)*8, wb = (tileid%7)*8;
    int tid = threadIdx.x;
    for(int ii=tid; ii<144*64; ii+=256){
        int sp = ii >> 6, cl = ii & 63;
        int ty = sp / 12, tx = sp % 12;
        int y = hb + ty - 2, x = wb + tx - 2;
        float v = 0.0f;
        if(y>=0 && y<HH && x>=0 && x<WW)
            v = qkv[((size_t)(n*HH+y)*WW + x)*768 + 512 + cg*64 + cl];
        tile[sp][cl] = v;
    }
    __syncthreads();
    int cl = tid & 63;
    int c = cg*64 + cl;
    float wv[25];
    #pragma unroll
    for(int t=0;t<25;t++) wv[t] = lw[c*25 + t];
    float bias = lb[c];
    for(int oi = tid; oi < 4096; oi += 256){
        int sp = oi >> 6;
        int py = sp >> 3, px = sp & 7;
        float a = bias;
        #pragma unroll
        for(int dy=0;dy<5;dy++)
            #pragma unroll
            for(int dx=0;dx<5;dx++)
                a += tile[(py+dy)*12 + px+dx][cl]*wv[dy*5+dx];
        size_t pix = (size_t)(n*HH + hb+py)*WW + wb+px;
        outb[pix*CC + c] = f2bf(attn[pix*CC + c] + a);
    }
}

// ---------------- global average pool over H,W (NHWC) ----------------
__global__ __launch_bounds__(256) void pool_kernel(const float* __restrict__ x, float* __restrict__ pooled){
    int n = blockIdx.x, c = threadIdx.x;
    float s=0.f;
    for(int p=0;p<3136;p++) s += x[((size_t)n*3136+p)*CC + c];
    pooled[n*CC+c] = s*(1.0f/3136.0f);
}

// ---------------- channel SE (two tiny FCs) ----------------
__global__ __launch_bounds__(256) void cse_kernel(const float* __restrict__ pooled,
                                                  const float* __restrict__ w1, const float* __restrict__ b1,
                                                  const float* __restrict__ w2, const float* __restrict__ b2,
                                                  float* __restrict__ cfac){
    int n = blockIdx.x, t = threadIdx.x;
    __shared__ float c1[16];
    if(t < 16){
        float s = b1[t];
        for(int c=0;c<CC;c++) s += pooled[n*CC+c]*w1[t*CC+c];
        c1[t] = fmaxf(s, 0.0f);
    }
    __syncthreads();
    float s = b2[t];
    #pragma unroll
    for(int j=0;j<16;j++) s += c1[j]*w2[t*16+j];
    cfac[n*CC+t] = sigmoid_f(s);
}

// ---------------- gating into padded bf16 conv input ----------------
__global__ __launch_bounds__(256) void gate_pad(const float* __restrict__ x, const float* __restrict__ s,
                                                const float* __restrict__ cfac, unsigned short* __restrict__ P){
    int pix = blockIdx.x;
    int n = pix / 3136; int rem = pix % 3136; int h = rem/56, w = rem%56;
    int c = threadIdx.x;
    float v = x[(size_t)pix*CC + c]*(cfac[n*CC+c] + s[(size_t)pix*CC + c]);
    // padded layout: guard(64 rows) + [n][58][58][256]
    size_t q = 64 + (size_t)n*3364 + (size_t)(h+1)*58 + (w+1);
    P[q*CC + c] = f2bf(v);
}

extern "C" void kernel_launch(void* const* d_in, const int* in_sizes, int n_in,
                              void* d_out, int out_size, void* d_ws, size_t ws_size,
                              hipStream_t stream){
    const float* x_in   = (const float*)d_in[0];
    const float* ln1w   = (const float*)d_in[1];
    const float* ln1b   = (const float*)d_in[2];
    const float* qkvw   = (const float*)d_in[3];
    const float* qkvb   = (const float*)d_in[4];
    const float* lepew  = (const float*)d_in[5];
    const float* lepeb  = (const float*)d_in[6];
    const float* wow    = (const float*)d_in[7];
    const float* wob    = (const float*)d_in[8];
    const float* ln2w   = (const float*)d_in[9];
    const float* ln2b   = (const float*)d_in[10];
    const float* mlp1w  = (const float*)d_in[11];
    const float* mlp1b  = (const float*)d_in[12];
    const float* mlp2w  = (const float*)d_in[13];
    const float* mlp2b  = (const float*)d_in[14];
    const float* cse1w  = (const float*)d_in[15];
    const float* cse1b  = (const float*)d_in[16];
    const float* cse2w  = (const float*)d_in[17];
    const float* cse2b  = (const float*)d_in[18];
    const float* ssew   = (const float*)d_in[19];
    const float* sseb   = (const float*)d_in[20];
    const float* convw  = (const float*)d_in[21];
    const float* convb  = (const float*)d_in[22];
    float* out = (float*)d_out;

    float* ws     = (float*)d_ws;
    float* bufx   = ws;                         // 6,422,528 f
    float* buftmp = bufx   + (size_t)PIX*CC;    // 6,422,528 f
    float* bufqkv = buftmp + (size_t)PIX*CC;    // 19,267,584 f
    float* qwin   = bufqkv + (size_t)PIX*768;   // 100,352 f
    float* kwin   = qwin + (size_t)NB*P2*CC;    // 100,352 f
    float* pooled = kwin + (size_t)NB*P2*CC;    // 2048
    float* cfac   = pooled + NB*CC;             // 2048
    int*   idxb   = (int*)(cfac + NB*CC);       // 2048 ints reserved
    unsigned short* bufxn = (unsigned short*)(cfac + NB*CC + 2048);   // 6,422,528 ush
    unsigned short* qkvbt = bufxn + (size_t)PIX*CC;                   // 4*768*256
    unsigned short* wobt  = qkvbt + (size_t)4*768*256;                // 4*256*256
    unsigned short* m1bt  = wobt  + (size_t)4*256*256;                // 4*1024*256
    unsigned short* m2bt  = m1bt  + (size_t)4*1024*256;               // 4*256*1024
    unsigned short* ssebt = m2bt  + (size_t)4*256*1024;               // 256*256
    unsigned short* cvbt  = ssebt + (size_t)256*256;                  // 9*256*256

    // conv-time overlays inside bufqkv (free by then)
    unsigned short* Ppad = (unsigned short*)bufqkv;                   // 27136 rows x 256 bf16
    unsigned short* hid  = (unsigned short*)bufqkv;                   // MLP hidden bf16 [25088,1024]

    // ---- weight prep (bf16, transposed to [N,K]) ----
    wtrans<<<dim3(24, 8, 4), dim3(32,32), 0, stream>>>(qkvw, qkvbt, 256, 768);
    wtrans<<<dim3(8, 8, 4),  dim3(32,32), 0, stream>>>(wow,  wobt,  256, 256);
    wtrans<<<dim3(32, 8, 4), dim3(32,32), 0, stream>>>(mlp1w, m1bt, 256, 1024);
    wtrans<<<dim3(8, 32, 4), dim3(32,32), 0, stream>>>(mlp2w, m2bt, 1024, 256);
    tobf16<<<256, 256, 0, stream>>>(ssew, ssebt, 65536);
    convw_reorder<<<2304, 256, 0, stream>>>(convw, cvbt);

    nchw_to_nhwc<<<dim3(NB*98, 8), dim3(32,32), 0, stream>>>(x_in, bufx);

    for(int i=0;i<4;i++){
        ln_bf16<<<PIX/4,256,0,stream>>>(bufx, ln1w+i*CC, ln1b+i*CC, bufxn);
        mfma_gemm<0,false,true,false><<<dim3(6,196),256,0,stream>>>(
            bufxn, qkvbt+(size_t)i*768*256, qkvb+i*768, nullptr, bufqkv, nullptr, PIX, 768, 256);
        winmean_kernel<<<NB*P2,256,0,stream>>>(bufqkv, qwin, kwin);
        route_kernel<<<NB*P2,64,0,stream>>>(qwin, kwin, idxb);
        attn_kernel<<<NB*P2*8,64,0,stream>>>(bufqkv, idxb, buftmp);
        lepe_kernel<<<dim3(49,4,NB),256,0,stream>>>(bufqkv, buftmp, lepew+(size_t)i*CC*25, lepeb+i*CC, bufxn);
        mfma_gemm<0,true,true,false><<<dim3(2,196),256,0,stream>>>(
            bufxn, wobt+(size_t)i*256*256, wob+i*CC, bufx, bufx, nullptr, PIX, 256, 256);
        ln_bf16<<<PIX/4,256,0,stream>>>(bufx, ln2w+i*CC, ln2b+i*CC, bufxn);
        mfma_gemm<1,false,false,true><<<dim3(8,196),256,0,stream>>>(
            bufxn, m1bt+(size_t)i*1024*256, mlp1b+i*1024, nullptr, nullptr, hid, PIX, 1024, 256);
        mfma_gemm<0,true,true,false><<<dim3(2,196),256,0,stream>>>(
            hid, m2bt+(size_t)i*256*1024, mlp2b+i*CC, bufx, bufx, nullptr, PIX, 256, 1024);
    }

    pool_kernel<<<NB,256,0,stream>>>(bufx, pooled);
    cse_kernel<<<NB,256,0,stream>>>(pooled, cse1w, cse1b, cse2w, cse2b, cfac);
    tobf16<<<PIX,256,0,stream>>>(bufx, bufxn, PIX*CC);
    mfma_gemm<2,false,true,false><<<dim3(2,196),256,0,stream>>>(
        bufxn, ssebt, sseb, nullptr, buftmp, nullptr, PIX, 256, 256);
    hipMemsetAsync(Ppad, 0, (size_t)27136*256*2, stream);
    gate_pad<<<PIX,256,0,stream>>>(bufx, buftmp, cfac, Ppad);
    conv_gemm<<<dim3(2,211),256,0,stream>>>(Ppad, cvbt, convb, out);
}

// Round 7
// 2212.706 us; speedup vs baseline: 3.7545x; 1.7437x over previous
//
#include <hip/hip_runtime.h>

#define PIX 25088
#define NB 8
#define HH 56
#define WW 56
#define CC 256
#define P2 49
#define TOPKN 4

typedef short s16x8 __attribute__((ext_vector_type(8)));
typedef float f32x4 __attribute__((ext_vector_type(4)));

__device__ __forceinline__ float gelu_f(float v){
    return 0.5f*v*(1.0f+erff(v*0.70710678118654752f));
}
__device__ __forceinline__ float sigmoid_f(float v){
    return 1.0f/(1.0f+__expf(-v));
}
__device__ __forceinline__ unsigned short f2bf(float f){
    union { float f; unsigned u; } x; x.f = f;
    unsigned r = x.u + 0x7fffu + ((x.u >> 16) & 1u);
    return (unsigned short)(r >> 16);
}
__device__ __forceinline__ float bf2f(unsigned short u){
    union { unsigned u; float f; } x; x.u = ((unsigned)u) << 16; return x.f;
}
__device__ __forceinline__ void gload_lds16(const void* g, void* l){
    __builtin_amdgcn_global_load_lds((const __attribute__((address_space(1))) void*)g,
                                     (__attribute__((address_space(3))) void*)l, 16, 0, 0);
}

// ---------------- NCHW -> NHWC transpose (tiled, f32) ----------------
__global__ __launch_bounds__(1024) void nchw_to_nhwc(const float* __restrict__ in, float* __restrict__ out){
    __shared__ float t[32][33];
    int pb = blockIdx.x;            // n * 98 + p-tile
    int n  = pb / 98;
    int p0 = (pb % 98) * 32;
    int c0 = blockIdx.y * 32;
    int tx = threadIdx.x, ty = threadIdx.y;
    t[ty][tx] = in[(size_t)(n*CC + c0+ty)*3136 + p0 + tx];
    __syncthreads();
    out[(size_t)(n*3136 + p0 + ty)*CC + c0 + tx] = t[tx][ty];
}

// ---------------- weight transpose+convert: f32 [K,N] (xLAYERS) -> bf16 [N,K] ----------------
__global__ __launch_bounds__(1024) void wtrans(const float* __restrict__ in, unsigned short* __restrict__ out,
                                               int K, int N){
    int layer = blockIdx.z;
    in  += (size_t)layer*K*N;
    out += (size_t)layer*K*N;
    __shared__ float t[32][33];
    int n0 = blockIdx.x*32, k0 = blockIdx.y*32;
    t[threadIdx.y][threadIdx.x] = in[(size_t)(k0+threadIdx.y)*N + n0 + threadIdx.x];
    __syncthreads();
    out[(size_t)(n0+threadIdx.y)*K + k0 + threadIdx.x] = f2bf(t[threadIdx.x][threadIdx.y]);
}

// ---------------- elementwise f32 -> bf16 ----------------
__global__ __launch_bounds__(256) void tobf16(const float* __restrict__ in, unsigned short* __restrict__ out, int n){
    int i = blockIdx.x*256 + threadIdx.x;
    if(i < n) out[i] = f2bf(in[i]);
}

// ---------------- conv weight reorder: [o][c][3][3] f32 -> [tap][o][c] bf16 ----------------
__global__ __launch_bounds__(256) void convw_reorder(const float* __restrict__ in, unsigned short* __restrict__ out){
    int idx = blockIdx.x*256 + threadIdx.x;      // over 256*256*9
    if(idx >= 256*256*9) return;
    int o = idx / (256*9); int rem = idx % (256*9); int c = rem/9; int t = rem%9;
    out[(size_t)t*65536 + o*256 + c] = f2bf(in[idx]);
}

// ---------------- LayerNorm over C=256, wave per row, bf16 out ----------------
__global__ __launch_bounds__(256) void ln_bf16(const float* __restrict__ x, const float* __restrict__ w,
                                               const float* __restrict__ b, unsigned short* __restrict__ y){
    int row = blockIdx.x*4 + (threadIdx.x >> 6);
    int lane = threadIdx.x & 63;
    const float4 v = *reinterpret_cast<const float4*>(&x[(size_t)row*CC + lane*4]);
    float s = v.x + v.y + v.z + v.w;
    #pragma unroll
    for(int off=32; off>0; off>>=1) s += __shfl_xor(s, off);
    float mu = s*(1.0f/CC);
    float d0=v.x-mu, d1=v.y-mu, d2=v.z-mu, d3=v.w-mu;
    float sq = d0*d0 + d1*d1 + d2*d2 + d3*d3;
    #pragma unroll
    for(int off=32; off>0; off>>=1) sq += __shfl_xor(sq, off);
    float rs = rsqrtf(sq*(1.0f/CC) + 1e-6f);
    const float4 wv = *reinterpret_cast<const float4*>(&w[lane*4]);
    const float4 bv = *reinterpret_cast<const float4*>(&b[lane*4]);
    ushort4 o;
    o.x = f2bf(d0*rs*wv.x + bv.x);
    o.y = f2bf(d1*rs*wv.y + bv.y);
    o.z = f2bf(d2*rs*wv.z + bv.z);
    o.w = f2bf(d3*rs*wv.w + bv.w);
    *reinterpret_cast<ushort4*>(&y[(size_t)row*CC + lane*4]) = o;
}

// ---------------- MFMA GEMM: A bf16 [M,K], Bt bf16 [N,K], 128x128 tile ----------------
// EPI: 0 none, 1 gelu, 2 sigmoid.  HASRES: add res[M,N] f32 after EPI.
// OUTF: write f32 C, OUTB: write bf16 C.
template<int EPI, bool HASRES, bool OUTF, bool OUTB>
__global__ __launch_bounds__(256) void mfma_gemm(
    const unsigned short* __restrict__ A, const unsigned short* __restrict__ Bt,
    const float* __restrict__ bias, const float* __restrict__ res,
    float* __restrict__ Cf, unsigned short* __restrict__ Cb,
    int M, int N, int K)
{
    __shared__ __align__(16) unsigned short As[4096];
    __shared__ __align__(16) unsigned short Bs[4096];
    const int tid = threadIdx.x;
    const int wid = tid >> 6, lane = tid & 63;
    const int row0 = blockIdx.y << 7, col0 = blockIdx.x << 7;
    const int wm = wid >> 1, wn = wid & 1;
    const int li = lane & 15, qq = lane >> 4;

    f32x4 acc[4][4] = {};
    const int nk = K >> 5;
    for(int kt=0; kt<nk; kt++){
        const int k0 = kt << 5;
        #pragma unroll
        for(int i=0;i<2;i++){
            int boff = wid*2048 + i*1024 + (lane<<4);  // byte slot in tile
            int row = boff >> 6;
            int t = (boff >> 4) & 3;
            int q = t ^ ((row >> 1) & 3);
            gload_lds16(A  + (size_t)(row0+row)*K + k0 + q*8, (char*)As + wid*2048 + i*1024);
            gload_lds16(Bt + (size_t)(col0+row)*K + k0 + q*8, (char*)Bs + wid*2048 + i*1024);
        }
        __syncthreads();
        s16x8 af[4], bfr[4];
        #pragma unroll
        for(int mi=0;mi<4;mi++){
            int r = (wm<<6) + (mi<<4) + li;
            af[mi] = *(const s16x8*)((const char*)As + r*64 + ((qq ^ ((r>>1)&3))<<4));
        }
        #pragma unroll
        for(int nj=0;nj<4;nj++){
            int r = (wn<<6) + (nj<<4) + li;
            bfr[nj] = *(const s16x8*)((const char*)Bs + r*64 + ((qq ^ ((r>>1)&3))<<4));
        }
        #pragma unroll
        for(int mi=0;mi<4;mi++)
            #pragma unroll
            for(int nj=0;nj<4;nj++)
                acc[mi][nj] = __builtin_amdgcn_mfma_f32_16x16x32_bf16(af[mi], bfr[nj], acc[mi][nj], 0,0,0);
        __syncthreads();
    }
    #pragma unroll
    for(int mi=0;mi<4;mi++){
        #pragma unroll
        for(int nj=0;nj<4;nj++){
            int col = col0 + (wn<<6) + (nj<<4) + li;
            float bv = bias ? bias[col] : 0.0f;
            #pragma unroll
            for(int rr=0;rr<4;rr++){
                int row = row0 + (wm<<6) + (mi<<4) + (qq<<2) + rr;
                float v = acc[mi][nj][rr] + bv;
                if(EPI==1) v = gelu_f(v);
                if(EPI==2) v = sigmoid_f(v);
                if(HASRES) v += res[(size_t)row*N + col];
                if(OUTF) Cf[(size_t)row*N + col] = v;
                if(OUTB) Cb[(size_t)row*N + col] = f2bf(v);
            }
        }
    }
}

// ---------------- conv 3x3 as 9-tap accumulated MFMA GEMM over padded image ----------------
// P: padded bf16 image base (guard of 64 rows precedes padded row 0). M=27008 rows.
// CBt: [9][256 out][256 in] bf16. Writes NCHW f32 out for valid pixels, + bias.
__global__ __launch_bounds__(256) void conv_gemm(
    const unsigned short* __restrict__ P, const unsigned short* __restrict__ CBt,
    const float* __restrict__ bias, float* __restrict__ out)
{
    __shared__ __align__(16) unsigned short As[4096];
    __shared__ __align__(16) unsigned short Bs[4096];
    const int tid = threadIdx.x;
    const int wid = tid >> 6, lane = tid & 63;
    const int row0 = blockIdx.y << 7, col0 = blockIdx.x << 7;
    const int wm = wid >> 1, wn = wid & 1;
    const int li = lane & 15, qq = lane >> 4;
    const int K = 256;

    f32x4 acc[4][4] = {};
    for(int tap=0; tap<9; tap++){
        int d = ((tap/3)-1)*58 + (tap%3) - 1;
        const unsigned short* A  = P + (size_t)(64 + d)*256;
        const unsigned short* Bt = CBt + (size_t)tap*65536;
        for(int kt=0; kt<8; kt++){
            const int k0 = kt << 5;
            #pragma unroll
            for(int i=0;i<2;i++){
                int boff = wid*2048 + i*1024 + (lane<<4);
                int row = boff >> 6;
                int t = (boff >> 4) & 3;
                int q = t ^ ((row >> 1) & 3);
                gload_lds16(A  + (size_t)(row0+row)*K + k0 + q*8, (char*)As + wid*2048 + i*1024);
                gload_lds16(Bt + (size_t)(col0+row)*K + k0 + q*8, (char*)Bs + wid*2048 + i*1024);
            }
            __syncthreads();
            s16x8 af[4], bfr[4];
            #pragma unroll
            for(int mi=0;mi<4;mi++){
                int r = (wm<<6) + (mi<<4) + li;
                af[mi] = *(const s16x8*)((const char*)As + r*64 + ((qq ^ ((r>>1)&3))<<4));
            }
            #pragma unroll
            for(int nj=0;nj<4;nj++){
                int r = (wn<<6) + (nj<<4) + li;
                bfr[nj] = *(const s16x8*)((const char*)Bs + r*64 + ((qq ^ ((r>>1)&3))<<4));
            }
            #pragma unroll
            for(int mi=0;mi<4;mi++)
                #pragma unroll
                for(int nj=0;nj<4;nj++)
                    acc[mi][nj] = __builtin_amdgcn_mfma_f32_16x16x32_bf16(af[mi], bfr[nj], acc[mi][nj], 0,0,0);
            __syncthreads();
        }
    }
    #pragma unroll
    for(int mi=0;mi<4;mi++){
        #pragma unroll
        for(int nj=0;nj<4;nj++){
            int col = col0 + (wn<<6) + (nj<<4) + li;
            float bv = bias[col];
            #pragma unroll
            for(int rr=0;rr<4;rr++){
                int prow = row0 + (wm<<6) + (mi<<4) + (qq<<2) + rr;
                if(prow < NB*3364){
                    int n = prow / 3364; int rem = prow % 3364;
                    int y = rem / 58, x = rem % 58;
                    if(y>=1 && y<57 && x>=1 && x<57){
                        out[(((size_t)n*CC + col)*HH + (y-1))*WW + (x-1)] = acc[mi][nj][rr] + bv;
                    }
                }
            }
        }
    }
}

// ---------------- region means of q and k ----------------
__global__ __launch_bounds__(256) void winmean_kernel(const float* __restrict__ qkv,
                                                      float* __restrict__ qwin, float* __restrict__ kwin){
    int b = blockIdx.x;      // n*49 + p
    int n = b / P2, p = b % P2;
    int c = threadIdx.x;
    int hb = (p/7)*8, wb = (p%7)*8;
    float sq=0.f, sk=0.f;
    for(int pixi=0;pixi<64;pixi++){
        int h = hb + (pixi>>3), w = wb + (pixi&7);
        const float* row = &qkv[((size_t)(n*HH+h)*WW + w)*768];
        sq += row[c];
        sk += row[256+c];
    }
    qwin[(size_t)b*CC+c] = sq*(1.0f/64.0f);
    kwin[(size_t)b*CC+c] = sk*(1.0f/64.0f);
}

// ---------------- routing logits + top-4 ----------------
__global__ __launch_bounds__(64) void route_kernel(const float* __restrict__ qwin, const float* __restrict__ kwin,
                                                   int* __restrict__ idxout){
    int b = blockIdx.x;      // n*49 + p
    int n = b / P2;
    int j = threadIdx.x;
    __shared__ float lg[64];
    float v = -1e30f;
    if(j < P2){
        const float* q = &qwin[(size_t)b*CC];
        const float* k = &kwin[(size_t)(n*P2+j)*CC];
        float s=0.f;
        for(int c=0;c<CC;c++) s += q[c]*k[c];
        v = s*0.0625f;
    }
    lg[j] = v;
    __syncthreads();
    if(j==0){
        for(int t=0;t<TOPKN;t++){
            int best=0; float bv=lg[0];
            for(int u=1;u<P2;u++) if(lg[u]>bv){bv=lg[u];best=u;}
            idxout[b*TOPKN+t]=best;
            lg[best]=-1e30f;
        }
    }
}

// ---------------- attention: one block per (n,p,head), 256 threads = 4 per query ----------------
// Thread t: query qi = t>>2, channel-quarter cq = t&3 (8 channels).
// K/V staged in LDS as bf16 (32 KB total -> 5 blocks/CU, 20 waves/CU).
// 32-dim score completed by 2-step shfl_xor within the 4-lane group.
__global__ __launch_bounds__(256) void attn_kernel(const float* __restrict__ qkv, const int* __restrict__ idx,
                                                   float* __restrict__ out){
    __shared__ __align__(16) unsigned short Kt[256*32];
    __shared__ __align__(16) unsigned short Vt[256*32];
    int b = blockIdx.x;
    int m = b & 7; int np = b >> 3;      // np = n*49+p
    int n = np / P2, p = np % P2;
    int tid = threadIdx.x;
    int hb = (p/7)*8, wb = (p%7)*8;
    // stage this head's K/V slices (gathered rows, f32 -> bf16)
    for(int ii=tid; ii<256*32; ii+=256){
        int j = ii >> 5, c = ii & 31;
        int t = j >> 6, pixi = j & 63;
        int r = idx[np*TOPKN + t];
        int h = (r/7)*8 + (pixi>>3), w = (r%7)*8 + (pixi&7);
        const float* rowp = &qkv[((size_t)(n*HH+h)*WW + w)*768 + m*32 + c];
        Kt[ii] = f2bf(rowp[256]);
        Vt[ii] = f2bf(rowp[512]);
    }
    __syncthreads();
    int qi = tid >> 2, cq = tid & 3;
    int h = hb + (qi>>3), w = wb + (qi&7);
    const float* qrow = &qkv[((size_t)(n*HH+h)*WW + w)*768 + m*32 + cq*8];
    float q[8];
    #pragma unroll
    for(int c=0;c<8;c++) q[c] = qrow[c]*0.0625f;
    float mx = -1e30f, l = 0.0f;
    float acc[8];
    #pragma unroll
    for(int c=0;c<8;c++) acc[c]=0.0f;
    for(int j=0;j<256;j++){
        s16x8 k8 = *(const s16x8*)&Kt[j*32 + cq*8];
        float s = 0.f;
        #pragma unroll
        for(int c=0;c<8;c++) s += q[c]*bf2f((unsigned short)k8[c]);
        s += __shfl_xor(s, 1);
        s += __shfl_xor(s, 2);           // all 4 lanes now hold full 32-dim score
        if(s > mx){
            float f = __expf(mx - s);
            l *= f;
            #pragma unroll
            for(int c=0;c<8;c++) acc[c]*=f;
            mx = s;
        }
        float pexp = __expf(s - mx);
        l += pexp;
        s16x8 v8 = *(const s16x8*)&Vt[j*32 + cq*8];
        #pragma unroll
        for(int c=0;c<8;c++) acc[c] += pexp*bf2f((unsigned short)v8[c]);
    }
    float inv = 1.0f/l;
    float* orow = &out[((size_t)(n*HH+h)*WW + w)*CC + m*32 + cq*8];
    #pragma unroll
    for(int c=0;c<8;c++) orow[c] = acc[c]*inv;
}

// ---------------- LEPE tiled: attn_out(f32) + dwconv5(v) -> bf16 ----------------
__global__ __launch_bounds__(256) void lepe_kernel(const float* __restrict__ qkv, const float* __restrict__ attn,
                                                   const float* __restrict__ lw, const float* __restrict__ lb,
                                                   unsigned short* __restrict__ outb){
    __shared__ float tile[144][64];     // 12x12 spatial halo x 64 channels
    int tileid = blockIdx.x;            // 0..48
    int cg = blockIdx.y;                // 0..3
    int n = blockIdx.z;
    int hb = (tileid/7)*8, wb = (tileid%7)*8;
    int tid = threadIdx.x;
    for(int ii=tid; ii<144*64; ii+=256){
        int sp = ii >> 6, cl = ii & 63;
        int ty = sp / 12, tx = sp % 12;
        int y = hb + ty - 2, x = wb + tx - 2;
        float v = 0.0f;
        if(y>=0 && y<HH && x>=0 && x<WW)
            v = qkv[((size_t)(n*HH+y)*WW + x)*768 + 512 + cg*64 + cl];
        tile[sp][cl] = v;
    }
    __syncthreads();
    int cl = tid & 63;
    int c = cg*64 + cl;
    float wv[25];
    #pragma unroll
    for(int t=0;t<25;t++) wv[t] = lw[c*25 + t];
    float bias = lb[c];
    for(int oi = tid; oi < 4096; oi += 256){
        int sp = oi >> 6;
        int py = sp >> 3, px = sp & 7;
        float a = bias;
        #pragma unroll
        for(int dy=0;dy<5;dy++)
            #pragma unroll
            for(int dx=0;dx<5;dx++)
                a += tile[(py+dy)*12 + px+dx][cl]*wv[dy*5+dx];
        size_t pix = (size_t)(n*HH + hb+py)*WW + wb+px;
        outb[pix*CC + c] = f2bf(attn[pix*CC + c] + a);
    }
}

// ---------------- global average pool over H,W (NHWC) ----------------
__global__ __launch_bounds__(256) void pool_kernel(const float* __restrict__ x, float* __restrict__ pooled){
    int n = blockIdx.x, c = threadIdx.x;
    float s=0.f;
    for(int p=0;p<3136;p++) s += x[((size_t)n*3136+p)*CC + c];
    pooled[n*CC+c] = s*(1.0f/3136.0f);
}

// ---------------- channel SE (two tiny FCs) ----------------
__global__ __launch_bounds__(256) void cse_kernel(const float* __restrict__ pooled,
                                                  const float* __restrict__ w1, const float* __restrict__ b1,
                                                  const float* __restrict__ w2, const float* __restrict__ b2,
                                                  float* __restrict__ cfac){
    int n = blockIdx.x, t = threadIdx.x;
    __shared__ float c1[16];
    if(t < 16){
        float s = b1[t];
        for(int c=0;c<CC;c++) s += pooled[n*CC+c]*w1[t*CC+c];
        c1[t] = fmaxf(s, 0.0f);
    }
    __syncthreads();
    float s = b2[t];
    #pragma unroll
    for(int j=0;j<16;j++) s += c1[j]*w2[t*16+j];
    cfac[n*CC+t] = sigmoid_f(s);
}

// ---------------- gating into padded bf16 conv input ----------------
__global__ __launch_bounds__(256) void gate_pad(const float* __restrict__ x, const float* __restrict__ s,
                                                const float* __restrict__ cfac, unsigned short* __restrict__ P){
    int pix = blockIdx.x;
    int n = pix / 3136; int rem = pix % 3136; int h = rem/56, w = rem%56;
    int c = threadIdx.x;
    float v = x[(size_t)pix*CC + c]*(cfac[n*CC+c] + s[(size_t)pix*CC + c]);
    // padded layout: guard(64 rows) + [n][58][58][256]
    size_t q = 64 + (size_t)n*3364 + (size_t)(h+1)*58 + (w+1);
    P[q*CC + c] = f2bf(v);
}

extern "C" void kernel_launch(void* const* d_in, const int* in_sizes, int n_in,
                              void* d_out, int out_size, void* d_ws, size_t ws_size,
                              hipStream_t stream){
    const float* x_in   = (const float*)d_in[0];
    const float* ln1w   = (const float*)d_in[1];
    const float* ln1b   = (const float*)d_in[2];
    const float* qkvw   = (const float*)d_in[3];
    const float* qkvb   = (const float*)d_in[4];
    const float* lepew  = (const float*)d_in[5];
    const float* lepeb  = (const float*)d_in[6];
    const float* wow    = (const float*)d_in[7];
    const float* wob    = (const float*)d_in[8];
    const float* ln2w   = (const float*)d_in[9];
    const float* ln2b   = (const float*)d_in[10];
    const float* mlp1w  = (const float*)d_in[11];
    const float* mlp1b  = (const float*)d_in[12];
    const float* mlp2w  = (const float*)d_in[13];
    const float* mlp2b  = (const float*)d_in[14];
    const float* cse1w  = (const float*)d_in[15];
    const float* cse1b  = (const float*)d_in[16];
    const float* cse2w  = (const float*)d_in[17];
    const float* cse2b  = (const float*)d_in[18];
    const float* ssew   = (const float*)d_in[19];
    const float* sseb   = (const float*)d_in[20];
    const float* convw  = (const float*)d_in[21];
    const float* convb  = (const float*)d_in[22];
    float* out = (float*)d_out;

    float* ws     = (float*)d_ws;
    float* bufx   = ws;                         // 6,422,528 f
    float* buftmp = bufx   + (size_t)PIX*CC;    // 6,422,528 f
    float* bufqkv = buftmp + (size_t)PIX*CC;    // 19,267,584 f
    float* qwin   = bufqkv + (size_t)PIX*768;   // 100,352 f
    float* kwin   = qwin + (size_t)NB*P2*CC;    // 100,352 f
    float* pooled = kwin + (size_t)NB*P2*CC;    // 2048
    float* cfac   = pooled + NB*CC;             // 2048
    int*   idxb   = (int*)(cfac + NB*CC);       // 2048 ints reserved
    unsigned short* bufxn = (unsigned short*)(cfac + NB*CC + 2048);   // 6,422,528 ush
    unsigned short* qkvbt = bufxn + (size_t)PIX*CC;                   // 4*768*256
    unsigned short* wobt  = qkvbt + (size_t)4*768*256;                // 4*256*256
    unsigned short* m1bt  = wobt  + (size_t)4*256*256;                // 4*1024*256
    unsigned short* m2bt  = m1bt  + (size_t)4*1024*256;               // 4*256*1024
    unsigned short* ssebt = m2bt  + (size_t)4*256*1024;               // 256*256
    unsigned short* cvbt  = ssebt + (size_t)256*256;                  // 9*256*256

    // conv-time overlays inside bufqkv (free by then)
    unsigned short* Ppad = (unsigned short*)bufqkv;                   // 27136 rows x 256 bf16
    unsigned short* hid  = (unsigned short*)bufqkv;                   // MLP hidden bf16 [25088,1024]

    // ---- weight prep (bf16, transposed to [N,K]) ----
    wtrans<<<dim3(24, 8, 4), dim3(32,32), 0, stream>>>(qkvw, qkvbt, 256, 768);
    wtrans<<<dim3(8, 8, 4),  dim3(32,32), 0, stream>>>(wow,  wobt,  256, 256);
    wtrans<<<dim3(32, 8, 4), dim3(32,32), 0, stream>>>(mlp1w, m1bt, 256, 1024);
    wtrans<<<dim3(8, 32, 4), dim3(32,32), 0, stream>>>(mlp2w, m2bt, 1024, 256);
    tobf16<<<256, 256, 0, stream>>>(ssew, ssebt, 65536);
    convw_reorder<<<2304, 256, 0, stream>>>(convw, cvbt);

    nchw_to_nhwc<<<dim3(NB*98, 8), dim3(32,32), 0, stream>>>(x_in, bufx);

    for(int i=0;i<4;i++){
        ln_bf16<<<PIX/4,256,0,stream>>>(bufx, ln1w+i*CC, ln1b+i*CC, bufxn);
        mfma_gemm<0,false,true,false><<<dim3(6,196),256,0,stream>>>(
            bufxn, qkvbt+(size_t)i*768*256, qkvb+i*768, nullptr, bufqkv, nullptr, PIX, 768, 256);
        winmean_kernel<<<NB*P2,256,0,stream>>>(bufqkv, qwin, kwin);
        route_kernel<<<NB*P2,64,0,stream>>>(qwin, kwin, idxb);
        attn_kernel<<<NB*P2*8,256,0,stream>>>(bufqkv, idxb, buftmp);
        lepe_kernel<<<dim3(49,4,NB),256,0,stream>>>(bufqkv, buftmp, lepew+(size_t)i*CC*25, lepeb+i*CC, bufxn);
        mfma_gemm<0,true,true,false><<<dim3(2,196),256,0,stream>>>(
            bufxn, wobt+(size_t)i*256*256, wob+i*CC, bufx, bufx, nullptr, PIX, 256, 256);
        ln_bf16<<<PIX/4,256,0,stream>>>(bufx, ln2w+i*CC, ln2b+i*CC, bufxn);
        mfma_gemm<1,false,false,true><<<dim3(8,196),256,0,stream>>>(
            bufxn, m1bt+(size_t)i*1024*256, mlp1b+i*1024, nullptr, nullptr, hid, PIX, 1024, 256);
        mfma_gemm<0,true,true,false><<<dim3(2,196),256,0,stream>>>(
            hid, m2bt+(size_t)i*256*1024, mlp2b+i*CC, bufx, bufx, nullptr, PIX, 256, 1024);
    }

    pool_kernel<<<NB,256,0,stream>>>(bufx, pooled);
    cse_kernel<<<NB,256,0,stream>>>(pooled, cse1w, cse1b, cse2w, cse2b, cfac);
    tobf16<<<PIX,256,0,stream>>>(bufx, bufxn, PIX*CC);
    mfma_gemm<2,false,true,false><<<dim3(2,196),256,0,stream>>>(
        bufxn, ssebt, sseb, nullptr, buftmp, nullptr, PIX, 256, 256);
    hipMemsetAsync(Ppad, 0, (size_t)27136*256*2, stream);
    gate_pad<<<PIX,256,0,stream>>>(bufx, buftmp, cfac, Ppad);
    conv_gemm<<<dim3(2,211),256,0,stream>>>(Ppad, cvbt, convb, out);
}

// Round 8
// 1382.391 us; speedup vs baseline: 6.0096x; 1.6006x over previous
//
#include <hip/hip_runtime.h>

#define PIX 25088
#define NB 8
#define HH 56
#define WW 56
#define CC 256
#define P2 49
#define TOPKN 4

typedef short s16x8 __attribute__((ext_vector_type(8)));
typedef float f32x4 __attribute__((ext_vector_type(4)));

__device__ __forceinline__ float gelu_f(float v){
    return 0.5f*v*(1.0f+erff(v*0.70710678118654752f));
}
__device__ __forceinline__ float sigmoid_f(float v){
    return 1.0f/(1.0f+__expf(-v));
}
__device__ __forceinline__ unsigned short f2bf(float f){
    union { float f; unsigned u; } x; x.f = f;
    unsigned r = x.u + 0x7fffu + ((x.u >> 16) & 1u);
    return (unsigned short)(r >> 16);
}
__device__ __forceinline__ float bf2f(unsigned short u){
    union { unsigned u; float f; } x; x.u = ((unsigned)u) << 16; return x.f;
}
__device__ __forceinline__ void gload_lds16(const void* g, void* l){
    __builtin_amdgcn_global_load_lds((const __attribute__((address_space(1))) void*)g,
                                     (__attribute__((address_space(3))) void*)l, 16, 0, 0);
}

// ---------------- NCHW -> NHWC transpose (tiled, f32) ----------------
__global__ __launch_bounds__(1024) void nchw_to_nhwc(const float* __restrict__ in, float* __restrict__ out){
    __shared__ float t[32][33];
    int pb = blockIdx.x;            // n * 98 + p-tile
    int n  = pb / 98;
    int p0 = (pb % 98) * 32;
    int c0 = blockIdx.y * 32;
    int tx = threadIdx.x, ty = threadIdx.y;
    t[ty][tx] = in[(size_t)(n*CC + c0+ty)*3136 + p0 + tx];
    __syncthreads();
    out[(size_t)(n*3136 + p0 + ty)*CC + c0 + tx] = t[tx][ty];
}

// ---------------- weight transpose+convert: f32 [K,N] (xLAYERS) -> bf16 [N,K] ----------------
__global__ __launch_bounds__(1024) void wtrans(const float* __restrict__ in, unsigned short* __restrict__ out,
                                               int K, int N){
    int layer = blockIdx.z;
    in  += (size_t)layer*K*N;
    out += (size_t)layer*K*N;
    __shared__ float t[32][33];
    int n0 = blockIdx.x*32, k0 = blockIdx.y*32;
    t[threadIdx.y][threadIdx.x] = in[(size_t)(k0+threadIdx.y)*N + n0 + threadIdx.x];
    __syncthreads();
    out[(size_t)(n0+threadIdx.y)*K + k0 + threadIdx.x] = f2bf(t[threadIdx.x][threadIdx.y]);
}

// ---------------- elementwise f32 -> bf16 ----------------
__global__ __launch_bounds__(256) void tobf16(const float* __restrict__ in, unsigned short* __restrict__ out, int n){
    int i = blockIdx.x*256 + threadIdx.x;
    if(i < n) out[i] = f2bf(in[i]);
}

// ---------------- conv weight reorder: [o][c][3][3] f32 -> [tap][o][c] bf16 ----------------
__global__ __launch_bounds__(256) void convw_reorder(const float* __restrict__ in, unsigned short* __restrict__ out){
    int idx = blockIdx.x*256 + threadIdx.x;      // over 256*256*9
    if(idx >= 256*256*9) return;
    int o = idx / (256*9); int rem = idx % (256*9); int c = rem/9; int t = rem%9;
    out[(size_t)t*65536 + o*256 + c] = f2bf(in[idx]);
}

// ---------------- LayerNorm over C=256, wave per row, bf16 out ----------------
__global__ __launch_bounds__(256) void ln_bf16(const float* __restrict__ x, const float* __restrict__ w,
                                               const float* __restrict__ b, unsigned short* __restrict__ y){
    int row = blockIdx.x*4 + (threadIdx.x >> 6);
    int lane = threadIdx.x & 63;
    const float4 v = *reinterpret_cast<const float4*>(&x[(size_t)row*CC + lane*4]);
    float s = v.x + v.y + v.z + v.w;
    #pragma unroll
    for(int off=32; off>0; off>>=1) s += __shfl_xor(s, off);
    float mu = s*(1.0f/CC);
    float d0=v.x-mu, d1=v.y-mu, d2=v.z-mu, d3=v.w-mu;
    float sq = d0*d0 + d1*d1 + d2*d2 + d3*d3;
    #pragma unroll
    for(int off=32; off>0; off>>=1) sq += __shfl_xor(sq, off);
    float rs = rsqrtf(sq*(1.0f/CC) + 1e-6f);
    const float4 wv = *reinterpret_cast<const float4*>(&w[lane*4]);
    const float4 bv = *reinterpret_cast<const float4*>(&b[lane*4]);
    ushort4 o;
    o.x = f2bf(d0*rs*wv.x + bv.x);
    o.y = f2bf(d1*rs*wv.y + bv.y);
    o.z = f2bf(d2*rs*wv.z + bv.z);
    o.w = f2bf(d3*rs*wv.w + bv.w);
    *reinterpret_cast<ushort4*>(&y[(size_t)row*CC + lane*4]) = o;
}

// ---------------- MFMA GEMM: A bf16 [M,K], Bt bf16 [N,K], 128x128 tile ----------------
// EPI: 0 none, 1 gelu, 2 sigmoid.  HASRES: add res[M,N] f32 after EPI.
// OUTF: write f32 C, OUTB: write bf16 C.
template<int EPI, bool HASRES, bool OUTF, bool OUTB>
__global__ __launch_bounds__(256) void mfma_gemm(
    const unsigned short* __restrict__ A, const unsigned short* __restrict__ Bt,
    const float* __restrict__ bias, const float* __restrict__ res,
    float* __restrict__ Cf, unsigned short* __restrict__ Cb,
    int M, int N, int K)
{
    __shared__ __align__(16) unsigned short As[4096];
    __shared__ __align__(16) unsigned short Bs[4096];
    const int tid = threadIdx.x;
    const int wid = tid >> 6, lane = tid & 63;
    const int row0 = blockIdx.y << 7, col0 = blockIdx.x << 7;
    const int wm = wid >> 1, wn = wid & 1;
    const int li = lane & 15, qq = lane >> 4;

    f32x4 acc[4][4] = {};
    const int nk = K >> 5;
    for(int kt=0; kt<nk; kt++){
        const int k0 = kt << 5;
        #pragma unroll
        for(int i=0;i<2;i++){
            int boff = wid*2048 + i*1024 + (lane<<4);  // byte slot in tile
            int row = boff >> 6;
            int t = (boff >> 4) & 3;
            int q = t ^ ((row >> 1) & 3);
            gload_lds16(A  + (size_t)(row0+row)*K + k0 + q*8, (char*)As + wid*2048 + i*1024);
            gload_lds16(Bt + (size_t)(col0+row)*K + k0 + q*8, (char*)Bs + wid*2048 + i*1024);
        }
        __syncthreads();
        s16x8 af[4], bfr[4];
        #pragma unroll
        for(int mi=0;mi<4;mi++){
            int r = (wm<<6) + (mi<<4) + li;
            af[mi] = *(const s16x8*)((const char*)As + r*64 + ((qq ^ ((r>>1)&3))<<4));
        }
        #pragma unroll
        for(int nj=0;nj<4;nj++){
            int r = (wn<<6) + (nj<<4) + li;
            bfr[nj] = *(const s16x8*)((const char*)Bs + r*64 + ((qq ^ ((r>>1)&3))<<4));
        }
        #pragma unroll
        for(int mi=0;mi<4;mi++)
            #pragma unroll
            for(int nj=0;nj<4;nj++)
                acc[mi][nj] = __builtin_amdgcn_mfma_f32_16x16x32_bf16(af[mi], bfr[nj], acc[mi][nj], 0,0,0);
        __syncthreads();
    }
    #pragma unroll
    for(int mi=0;mi<4;mi++){
        #pragma unroll
        for(int nj=0;nj<4;nj++){
            int col = col0 + (wn<<6) + (nj<<4) + li;
            float bv = bias ? bias[col] : 0.0f;
            #pragma unroll
            for(int rr=0;rr<4;rr++){
                int row = row0 + (wm<<6) + (mi<<4) + (qq<<2) + rr;
                float v = acc[mi][nj][rr] + bv;
                if(EPI==1) v = gelu_f(v);
                if(EPI==2) v = sigmoid_f(v);
                if(HASRES) v += res[(size_t)row*N + col];
                if(OUTF) Cf[(size_t)row*N + col] = v;
                if(OUTB) Cb[(size_t)row*N + col] = f2bf(v);
            }
        }
    }
}

// ---------------- conv 3x3 as 9-tap accumulated MFMA GEMM over padded image ----------------
__global__ __launch_bounds__(256) void conv_gemm(
    const unsigned short* __restrict__ P, const unsigned short* __restrict__ CBt,
    const float* __restrict__ bias, float* __restrict__ out)
{
    __shared__ __align__(16) unsigned short As[4096];
    __shared__ __align__(16) unsigned short Bs[4096];
    const int tid = threadIdx.x;
    const int wid = tid >> 6, lane = tid & 63;
    const int row0 = blockIdx.y << 7, col0 = blockIdx.x << 7;
    const int wm = wid >> 1, wn = wid & 1;
    const int li = lane & 15, qq = lane >> 4;
    const int K = 256;

    f32x4 acc[4][4] = {};
    for(int tap=0; tap<9; tap++){
        int d = ((tap/3)-1)*58 + (tap%3) - 1;
        const unsigned short* A  = P + (size_t)(64 + d)*256;
        const unsigned short* Bt = CBt + (size_t)tap*65536;
        for(int kt=0; kt<8; kt++){
            const int k0 = kt << 5;
            #pragma unroll
            for(int i=0;i<2;i++){
                int boff = wid*2048 + i*1024 + (lane<<4);
                int row = boff >> 6;
                int t = (boff >> 4) & 3;
                int q = t ^ ((row >> 1) & 3);
                gload_lds16(A  + (size_t)(row0+row)*K + k0 + q*8, (char*)As + wid*2048 + i*1024);
                gload_lds16(Bt + (size_t)(col0+row)*K + k0 + q*8, (char*)Bs + wid*2048 + i*1024);
            }
            __syncthreads();
            s16x8 af[4], bfr[4];
            #pragma unroll
            for(int mi=0;mi<4;mi++){
                int r = (wm<<6) + (mi<<4) + li;
                af[mi] = *(const s16x8*)((const char*)As + r*64 + ((qq ^ ((r>>1)&3))<<4));
            }
            #pragma unroll
            for(int nj=0;nj<4;nj++){
                int r = (wn<<6) + (nj<<4) + li;
                bfr[nj] = *(const s16x8*)((const char*)Bs + r*64 + ((qq ^ ((r>>1)&3))<<4));
            }
            #pragma unroll
            for(int mi=0;mi<4;mi++)
                #pragma unroll
                for(int nj=0;nj<4;nj++)
                    acc[mi][nj] = __builtin_amdgcn_mfma_f32_16x16x32_bf16(af[mi], bfr[nj], acc[mi][nj], 0,0,0);
            __syncthreads();
        }
    }
    #pragma unroll
    for(int mi=0;mi<4;mi++){
        #pragma unroll
        for(int nj=0;nj<4;nj++){
            int col = col0 + (wn<<6) + (nj<<4) + li;
            float bv = bias[col];
            #pragma unroll
            for(int rr=0;rr<4;rr++){
                int prow = row0 + (wm<<6) + (mi<<4) + (qq<<2) + rr;
                if(prow < NB*3364){
                    int n = prow / 3364; int rem = prow % 3364;
                    int y = rem / 58, x = rem % 58;
                    if(y>=1 && y<57 && x>=1 && x<57){
                        out[(((size_t)n*CC + col)*HH + (y-1))*WW + (x-1)] = acc[mi][nj][rr] + bv;
                    }
                }
            }
        }
    }
}

// ---------------- region means of q and k ----------------
__global__ __launch_bounds__(256) void winmean_kernel(const float* __restrict__ qkv,
                                                      float* __restrict__ qwin, float* __restrict__ kwin){
    int b = blockIdx.x;      // n*49 + p
    int n = b / P2, p = b % P2;
    int c = threadIdx.x;
    int hb = (p/7)*8, wb = (p%7)*8;
    float sq=0.f, sk=0.f;
    for(int pixi=0;pixi<64;pixi++){
        int h = hb + (pixi>>3), w = wb + (pixi&7);
        const float* row = &qkv[((size_t)(n*HH+h)*WW + w)*768];
        sq += row[c];
        sk += row[256+c];
    }
    qwin[(size_t)b*CC+c] = sq*(1.0f/64.0f);
    kwin[(size_t)b*CC+c] = sk*(1.0f/64.0f);
}

// ---------------- routing logits + top-4 ----------------
__global__ __launch_bounds__(64) void route_kernel(const float* __restrict__ qwin, const float* __restrict__ kwin,
                                                   int* __restrict__ idxout){
    int b = blockIdx.x;      // n*49 + p
    int n = b / P2;
    int j = threadIdx.x;
    __shared__ float lg[64];
    float v = -1e30f;
    if(j < P2){
        const float* q = &qwin[(size_t)b*CC];
        const float* k = &kwin[(size_t)(n*P2+j)*CC];
        float s=0.f;
        for(int c=0;c<CC;c++) s += q[c]*k[c];
        v = s*0.0625f;
    }
    lg[j] = v;
    __syncthreads();
    if(j==0){
        for(int t=0;t<TOPKN;t++){
            int best=0; float bv=lg[0];
            for(int u=1;u<P2;u++) if(lg[u]>bv){bv=lg[u];best=u;}
            idxout[b*TOPKN+t]=best;
            lg[best]=-1e30f;
        }
    }
}

// ---------------- MFMA flash attention: ONE WAVE per (n,p,head) ----------------
// S^T = K*Q^T via mfma (A=K rows, B=Q rows): D col=query=lane&15, row=key=(lane>>4)*4+reg.
// Softmax per query column: local 8 + shfl_xor(16,32); m/l live at lane&15 across 4 qf frags.
// P^T -> LDS (bf16, XOR-swizzled), read back as B-frags.
// O^T = V^T*P^T: A=V^T built from global scalar reads; C col=query matches softmax layout.
__global__ __launch_bounds__(64) void attn_kernel(const float* __restrict__ qkv, const int* __restrict__ idx,
                                                  float* __restrict__ out){
    __shared__ __align__(16) unsigned short P_lds[64*32];   // [q][key] bf16, byte ^= (q&3)<<4
    __shared__ int pixo[256];                               // gathered global pixel index per key
    int b = blockIdx.x;
    int m = b & 7; int np = b >> 3;      // np = n*49+p
    int n = np / P2, p = np % P2;
    int lane = threadIdx.x;
    int li = lane & 15, g = lane >> 4;
    int hb = (p/7)*8, wb = (p%7)*8;

    #pragma unroll
    for(int t4=0;t4<4;t4++){
        int r = idx[np*TOPKN + t4];           // wave-uniform
        int pixi = lane;
        int h = (r/7)*8 + (pixi>>3), w = (r%7)*8 + (pixi&7);
        pixo[t4*64 + lane] = (n*HH+h)*WW + w;
    }
    __syncthreads();

    // Q fragments (B-operand of S^T): row=q=li+qf*16, k=ch=g*8+j; scale folds 1/16 and log2(e)
    const float QS = 0.0625f * 1.44269504088896f;
    s16x8 qfr[4];
    #pragma unroll
    for(int q4=0;q4<4;q4++){
        int q = q4*16 + li;
        int h = hb + (q>>3), w = wb + (q&7);
        const float* qr = &qkv[((size_t)(n*HH+h)*WW + w)*768 + m*32 + g*8];
        s16x8 f;
        #pragma unroll
        for(int j=0;j<8;j++) f[j] = (short)f2bf(qr[j]*QS);
        qfr[q4] = f;
    }

    f32x4 ot[2][4] = {};                 // O^T frags [chf][qf]
    float mx[4], lsum[4];
    #pragma unroll
    for(int q4=0;q4<4;q4++){ mx[q4] = -3e38f; lsum[q4] = 0.0f; }

    for(int kb=0; kb<8; kb++){
        // ---- S^T tile (32 keys x 64 queries) ----
        f32x4 st[2][4] = {};
        #pragma unroll
        for(int kf=0;kf<2;kf++){
            int key = kb*32 + kf*16 + li;
            const float* kr = &qkv[(size_t)pixo[key]*768 + 256 + m*32 + g*8];
            s16x8 kfrag;
            #pragma unroll
            for(int j=0;j<8;j++) kfrag[j] = (short)f2bf(kr[j]);
            #pragma unroll
            for(int q4=0;q4<4;q4++)
                st[kf][q4] = __builtin_amdgcn_mfma_f32_16x16x32_bf16(kfrag, qfr[q4], st[kf][q4], 0,0,0);
        }
        // ---- online softmax per query column (q = li + q4*16) ----
        #pragma unroll
        for(int q4=0;q4<4;q4++){
            float pm = st[0][q4][0];
            #pragma unroll
            for(int r=1;r<4;r++) pm = fmaxf(pm, st[0][q4][r]);
            #pragma unroll
            for(int r=0;r<4;r++) pm = fmaxf(pm, st[1][q4][r]);
            pm = fmaxf(pm, __shfl_xor(pm, 16));
            pm = fmaxf(pm, __shfl_xor(pm, 32));
            float mnew = fmaxf(mx[q4], pm);
            float fsc = exp2f(mx[q4] - mnew);
            mx[q4] = mnew;
            float ps = 0.0f;
            #pragma unroll
            for(int kf=0;kf<2;kf++)
                #pragma unroll
                for(int r=0;r<4;r++){
                    float pv = exp2f(st[kf][q4][r] - mnew);
                    st[kf][q4][r] = pv;
                    ps += pv;
                }
            ps += __shfl_xor(ps, 16);
            ps += __shfl_xor(ps, 32);
            lsum[q4] = lsum[q4]*fsc + ps;
            #pragma unroll
            for(int chf=0;chf<2;chf++)
                #pragma unroll
                for(int r=0;r<4;r++) ot[chf][q4][r] *= fsc;
        }
        // ---- write P^T to LDS: P_lds[q][key_local], keys packed in pairs along regs ----
        #pragma unroll
        for(int q4=0;q4<4;q4++){
            int q = q4*16 + li;
            #pragma unroll
            for(int kf=0;kf<2;kf++){
                unsigned lo = ((unsigned)f2bf(st[kf][q4][0])) | (((unsigned)f2bf(st[kf][q4][1]))<<16);
                unsigned hi = ((unsigned)f2bf(st[kf][q4][2])) | (((unsigned)f2bf(st[kf][q4][3]))<<16);
                int byte = (q*64 + kf*32 + g*8) ^ ((q&3)<<4);
                *reinterpret_cast<uint2*>((char*)P_lds + byte) = make_uint2(lo, hi);
            }
        }
        __syncthreads();
        // ---- read P^T back as B-frags: row=q=li+q4*16, k=key=g*8+j (16B contiguous) ----
        s16x8 pfr[4];
        #pragma unroll
        for(int q4=0;q4<4;q4++){
            int q = q4*16 + li;
            int byte = (q*64 + g*16) ^ ((q&3)<<4);
            pfr[q4] = *reinterpret_cast<const s16x8*>((const char*)P_lds + byte);
        }
        // ---- O^T += V^T * P^T ; A=V^T: row=ch=chf*16+li, k=key=g*8+j (scalar global reads) ----
        #pragma unroll
        for(int chf=0;chf<2;chf++){
            s16x8 vfr;
            #pragma unroll
            for(int j=0;j<8;j++){
                int key = kb*32 + g*8 + j;
                vfr[j] = (short)f2bf(qkv[(size_t)pixo[key]*768 + 512 + m*32 + chf*16 + li]);
            }
            #pragma unroll
            for(int q4=0;q4<4;q4++)
                ot[chf][q4] = __builtin_amdgcn_mfma_f32_16x16x32_bf16(vfr, pfr[q4], ot[chf][q4], 0,0,0);
        }
        __syncthreads();
    }
    // ---- epilogue: out[pixel(q)][m*32 + ch] = O^T[ch][q] / l[q] ----
    #pragma unroll
    for(int q4=0;q4<4;q4++){
        int q = q4*16 + li;
        int h = hb + (q>>3), w = wb + (q&7);
        float inv = 1.0f / lsum[q4];
        float* orow = &out[((size_t)(n*HH+h)*WW + w)*CC + m*32];
        #pragma unroll
        for(int chf=0;chf<2;chf++)
            #pragma unroll
            for(int r=0;r<4;r++)
                orow[chf*16 + g*4 + r] = ot[chf][q4][r]*inv;
    }
}

// ---------------- LEPE tiled: attn_out(f32) + dwconv5(v) -> bf16 ----------------
__global__ __launch_bounds__(256) void lepe_kernel(const float* __restrict__ qkv, const float* __restrict__ attn,
                                                   const float* __restrict__ lw, const float* __restrict__ lb,
                                                   unsigned short* __restrict__ outb){
    __shared__ float tile[144][64];     // 12x12 spatial halo x 64 channels
    int tileid = blockIdx.x;            // 0..48
    int cg = blockIdx.y;                // 0..3
    int n = blockIdx.z;
    int hb = (tileid/7)*8, wb = (tileid%7)*8;
    int tid = threadIdx.x;
    for(int ii=tid; ii<144*64; ii+=256){
        int sp = ii >> 6, cl = ii & 63;
        int ty = sp / 12, tx = sp % 12;
        int y = hb + ty - 2, x = wb + tx - 2;
        float v = 0.0f;
        if(y>=0 && y<HH && x>=0 && x<WW)
            v = qkv[((size_t)(n*HH+y)*WW + x)*768 + 512 + cg*64 + cl];
        tile[sp][cl] = v;
    }
    __syncthreads();
    int cl = tid & 63;
    int c = cg*64 + cl;
    float wv[25];
    #pragma unroll
    for(int t=0;t<25;t++) wv[t] = lw[c*25 + t];
    float bias = lb[c];
    for(int oi = tid; oi < 4096; oi += 256){
        int sp = oi >> 6;
        int py = sp >> 3, px = sp & 7;
        float a = bias;
        #pragma unroll
        for(int dy=0;dy<5;dy++)
            #pragma unroll
            for(int dx=0;dx<5;dx++)
                a += tile[(py+dy)*12 + px+dx][cl]*wv[dy*5+dx];
        size_t pix = (size_t)(n*HH + hb+py)*WW + wb+px;
        outb[pix*CC + c] = f2bf(attn[pix*CC + c] + a);
    }
}

// ---------------- global average pool over H,W (NHWC) ----------------
__global__ __launch_bounds__(256) void pool_kernel(const float* __restrict__ x, float* __restrict__ pooled){
    int n = blockIdx.x, c = threadIdx.x;
    float s=0.f;
    for(int p=0;p<3136;p++) s += x[((size_t)n*3136+p)*CC + c];
    pooled[n*CC+c] = s*(1.0f/3136.0f);
}

// ---------------- channel SE (two tiny FCs) ----------------
__global__ __launch_bounds__(256) void cse_kernel(const float* __restrict__ pooled,
                                                  const float* __restrict__ w1, const float* __restrict__ b1,
                                                  const float* __restrict__ w2, const float* __restrict__ b2,
                                                  float* __restrict__ cfac){
    int n = blockIdx.x, t = threadIdx.x;
    __shared__ float c1[16];
    if(t < 16){
        float s = b1[t];
        for(int c=0;c<CC;c++) s += pooled[n*CC+c]*w1[t*CC+c];
        c1[t] = fmaxf(s, 0.0f);
    }
    __syncthreads();
    float s = b2[t];
    #pragma unroll
    for(int j=0;j<16;j++) s += c1[j]*w2[t*16+j];
    cfac[n*CC+t] = sigmoid_f(s);
}

// ---------------- gating into padded bf16 conv input ----------------
__global__ __launch_bounds__(256) void gate_pad(const float* __restrict__ x, const float* __restrict__ s,
                                                const float* __restrict__ cfac, unsigned short* __restrict__ P){
    int pix = blockIdx.x;
    int n = pix / 3136; int rem = pix % 3136; int h = rem/56, w = rem%56;
    int c = threadIdx.x;
    float v = x[(size_t)pix*CC + c]*(cfac[n*CC+c] + s[(size_t)pix*CC + c]);
    // padded layout: guard(64 rows) + [n][58][58][256]
    size_t q = 64 + (size_t)n*3364 + (size_t)(h+1)*58 + (w+1);
    P[q*CC + c] = f2bf(v);
}

extern "C" void kernel_launch(void* const* d_in, const int* in_sizes, int n_in,
                              void* d_out, int out_size, void* d_ws, size_t ws_size,
                              hipStream_t stream){
    const float* x_in   = (const float*)d_in[0];
    const float* ln1w   = (const float*)d_in[1];
    const float* ln1b   = (const float*)d_in[2];
    const float* qkvw   = (const float*)d_in[3];
    const float* qkvb   = (const float*)d_in[4];
    const float* lepew  = (const float*)d_in[5];
    const float* lepeb  = (const float*)d_in[6];
    const float* wow    = (const float*)d_in[7];
    const float* wob    = (const float*)d_in[8];
    const float* ln2w   = (const float*)d_in[9];
    const float* ln2b   = (const float*)d_in[10];
    const float* mlp1w  = (const float*)d_in[11];
    const float* mlp1b  = (const float*)d_in[12];
    const float* mlp2w  = (const float*)d_in[13];
    const float* mlp2b  = (const float*)d_in[14];
    const float* cse1w  = (const float*)d_in[15];
    const float* cse1b  = (const float*)d_in[16];
    const float* cse2w  = (const float*)d_in[17];
    const float* cse2b  = (const float*)d_in[18];
    const float* ssew   = (const float*)d_in[19];
    const float* sseb   = (const float*)d_in[20];
    const float* convw  = (const float*)d_in[21];
    const float* convb  = (const float*)d_in[22];
    float* out = (float*)d_out;

    float* ws     = (float*)d_ws;
    float* bufx   = ws;                         // 6,422,528 f
    float* buftmp = bufx   + (size_t)PIX*CC;    // 6,422,528 f
    float* bufqkv = buftmp + (size_t)PIX*CC;    // 19,267,584 f
    float* qwin   = bufqkv + (size_t)PIX*768;   // 100,352 f
    float* kwin   = qwin + (size_t)NB*P2*CC;    // 100,352 f
    float* pooled = kwin + (size_t)NB*P2*CC;    // 2048
    float* cfac   = pooled + NB*CC;             // 2048
    int*   idxb   = (int*)(cfac + NB*CC);       // 2048 ints reserved
    unsigned short* bufxn = (unsigned short*)(cfac + NB*CC + 2048);   // 6,422,528 ush
    unsigned short* qkvbt = bufxn + (size_t)PIX*CC;                   // 4*768*256
    unsigned short* wobt  = qkvbt + (size_t)4*768*256;                // 4*256*256
    unsigned short* m1bt  = wobt  + (size_t)4*256*256;                // 4*1024*256
    unsigned short* m2bt  = m1bt  + (size_t)4*1024*256;               // 4*256*1024
    unsigned short* ssebt = m2bt  + (size_t)4*256*1024;               // 256*256
    unsigned short* cvbt  = ssebt + (size_t)256*256;                  // 9*256*256

    // conv-time overlays inside bufqkv (free by then)
    unsigned short* Ppad = (unsigned short*)bufqkv;                   // 27136 rows x 256 bf16
    unsigned short* hid  = (unsigned short*)bufqkv;                   // MLP hidden bf16 [25088,1024]

    // ---- weight prep (bf16, transposed to [N,K]) ----
    wtrans<<<dim3(24, 8, 4), dim3(32,32), 0, stream>>>(qkvw, qkvbt, 256, 768);
    wtrans<<<dim3(8, 8, 4),  dim3(32,32), 0, stream>>>(wow,  wobt,  256, 256);
    wtrans<<<dim3(32, 8, 4), dim3(32,32), 0, stream>>>(mlp1w, m1bt, 256, 1024);
    wtrans<<<dim3(8, 32, 4), dim3(32,32), 0, stream>>>(mlp2w, m2bt, 1024, 256);
    tobf16<<<256, 256, 0, stream>>>(ssew, ssebt, 65536);
    convw_reorder<<<2304, 256, 0, stream>>>(convw, cvbt);

    nchw_to_nhwc<<<dim3(NB*98, 8), dim3(32,32), 0, stream>>>(x_in, bufx);

    for(int i=0;i<4;i++){
        ln_bf16<<<PIX/4,256,0,stream>>>(bufx, ln1w+i*CC, ln1b+i*CC, bufxn);
        mfma_gemm<0,false,true,false><<<dim3(6,196),256,0,stream>>>(
            bufxn, qkvbt+(size_t)i*768*256, qkvb+i*768, nullptr, bufqkv, nullptr, PIX, 768, 256);
        winmean_kernel<<<NB*P2,256,0,stream>>>(bufqkv, qwin, kwin);
        route_kernel<<<NB*P2,64,0,stream>>>(qwin, kwin, idxb);
        attn_kernel<<<NB*P2*8,64,0,stream>>>(bufqkv, idxb, buftmp);
        lepe_kernel<<<dim3(49,4,NB),256,0,stream>>>(bufqkv, buftmp, lepew+(size_t)i*CC*25, lepeb+i*CC, bufxn);
        mfma_gemm<0,true,true,false><<<dim3(2,196),256,0,stream>>>(
            bufxn, wobt+(size_t)i*256*256, wob+i*CC, bufx, bufx, nullptr, PIX, 256, 256);
        ln_bf16<<<PIX/4,256,0,stream>>>(bufx, ln2w+i*CC, ln2b+i*CC, bufxn);
        mfma_gemm<1,false,false,true><<<dim3(8,196),256,0,stream>>>(
            bufxn, m1bt+(size_t)i*1024*256, mlp1b+i*1024, nullptr, nullptr, hid, PIX, 1024, 256);
        mfma_gemm<0,true,true,false><<<dim3(2,196),256,0,stream>>>(
            hid, m2bt+(size_t)i*256*1024, mlp2b+i*CC, bufx, bufx, nullptr, PIX, 256, 1024);
    }

    pool_kernel<<<NB,256,0,stream>>>(bufx, pooled);
    cse_kernel<<<NB,256,0,stream>>>(pooled, cse1w, cse1b, cse2w, cse2b, cfac);
    tobf16<<<PIX,256,0,stream>>>(bufx, bufxn, PIX*CC);
    mfma_gemm<2,false,true,false><<<dim3(2,196),256,0,stream>>>(
        bufxn, ssebt, sseb, nullptr, buftmp, nullptr, PIX, 256, 256);
    hipMemsetAsync(Ppad, 0, (size_t)27136*256*2, stream);
    gate_pad<<<PIX,256,0,stream>>>(bufx, buftmp, cfac, Ppad);
    conv_gemm<<<dim3(2,211),256,0,stream>>>(Ppad, cvbt, convb, out);
}

// Round 11
// 1282.516 us; speedup vs baseline: 6.4776x; 1.0779x over previous
//
#include <hip/hip_runtime.h>

#define PIX 25088
#define NB 8
#define HH 56
#define WW 56
#define CC 256
#define P2 49
#define TOPKN 4

typedef short s16x8 __attribute__((ext_vector_type(8)));
typedef float f32x4 __attribute__((ext_vector_type(4)));

__device__ __forceinline__ float gelu_f(float v){
    return 0.5f*v*(1.0f+erff(v*0.70710678118654752f));
}
__device__ __forceinline__ float sigmoid_f(float v){
    return 1.0f/(1.0f+__expf(-v));
}
__device__ __forceinline__ unsigned short f2bf(float f){
    union { float f; unsigned u; } x; x.f = f;
    unsigned r = x.u + 0x7fffu + ((x.u >> 16) & 1u);
    return (unsigned short)(r >> 16);
}
__device__ __forceinline__ float bf2f(unsigned short u){
    union { unsigned u; float f; } x; x.u = ((unsigned)u) << 16; return x.f;
}
__device__ __forceinline__ void gload_lds16(const void* g, void* l){
    __builtin_amdgcn_global_load_lds((const __attribute__((address_space(1))) void*)g,
                                     (__attribute__((address_space(3))) void*)l, 16, 0, 0);
}

// ---------------- NCHW -> NHWC transpose (tiled, f32) ----------------
__global__ __launch_bounds__(1024) void nchw_to_nhwc(const float* __restrict__ in, float* __restrict__ out){
    __shared__ float t[32][33];
    int pb = blockIdx.x;            // n * 98 + p-tile
    int n  = pb / 98;
    int p0 = (pb % 98) * 32;
    int c0 = blockIdx.y * 32;
    int tx = threadIdx.x, ty = threadIdx.y;
    t[ty][tx] = in[(size_t)(n*CC + c0+ty)*3136 + p0 + tx];
    __syncthreads();
    out[(size_t)(n*3136 + p0 + ty)*CC + c0 + tx] = t[tx][ty];
}

// ---------------- weight transpose+convert: f32 [K,N] (xLAYERS) -> bf16 [N,K] ----------------
__global__ __launch_bounds__(1024) void wtrans(const float* __restrict__ in, unsigned short* __restrict__ out,
                                               int K, int N){
    int layer = blockIdx.z;
    in  += (size_t)layer*K*N;
    out += (size_t)layer*K*N;
    __shared__ float t[32][33];
    int n0 = blockIdx.x*32, k0 = blockIdx.y*32;
    t[threadIdx.y][threadIdx.x] = in[(size_t)(k0+threadIdx.y)*N + n0 + threadIdx.x];
    __syncthreads();
    out[(size_t)(n0+threadIdx.y)*K + k0 + threadIdx.x] = f2bf(t[threadIdx.x][threadIdx.y]);
}

// ---------------- elementwise f32 -> bf16 ----------------
__global__ __launch_bounds__(256) void tobf16(const float* __restrict__ in, unsigned short* __restrict__ out, int n){
    int i = blockIdx.x*256 + threadIdx.x;
    if(i < n) out[i] = f2bf(in[i]);
}

// ---------------- conv weight reorder: [o][c][3][3] f32 -> [tap][o][c] bf16 ----------------
__global__ __launch_bounds__(256) void convw_reorder(const float* __restrict__ in, unsigned short* __restrict__ out){
    int idx = blockIdx.x*256 + threadIdx.x;      // over 256*256*9
    if(idx >= 256*256*9) return;
    int o = idx / (256*9); int rem = idx % (256*9); int c = rem/9; int t = rem%9;
    out[(size_t)t*65536 + o*256 + c] = f2bf(in[idx]);
}

// ---------------- LayerNorm over C=256, wave per row, bf16 out ----------------
__global__ __launch_bounds__(256) void ln_bf16(const float* __restrict__ x, const float* __restrict__ w,
                                               const float* __restrict__ b, unsigned short* __restrict__ y){
    int row = blockIdx.x*4 + (threadIdx.x >> 6);
    int lane = threadIdx.x & 63;
    const float4 v = *reinterpret_cast<const float4*>(&x[(size_t)row*CC + lane*4]);
    float s = v.x + v.y + v.z + v.w;
    #pragma unroll
    for(int off=32; off>0; off>>=1) s += __shfl_xor(s, off);
    float mu = s*(1.0f/CC);
    float d0=v.x-mu, d1=v.y-mu, d2=v.z-mu, d3=v.w-mu;
    float sq = d0*d0 + d1*d1 + d2*d2 + d3*d3;
    #pragma unroll
    for(int off=32; off>0; off>>=1) sq += __shfl_xor(sq, off);
    float rs = rsqrtf(sq*(1.0f/CC) + 1e-6f);
    const float4 wv = *reinterpret_cast<const float4*>(&w[lane*4]);
    const float4 bv = *reinterpret_cast<const float4*>(&b[lane*4]);
    ushort4 o;
    o.x = f2bf(d0*rs*wv.x + bv.x);
    o.y = f2bf(d1*rs*wv.y + bv.y);
    o.z = f2bf(d2*rs*wv.z + bv.z);
    o.w = f2bf(d3*rs*wv.w + bv.w);
    *reinterpret_cast<ushort4*>(&y[(size_t)row*CC + lane*4]) = o;
}

// ---------------- MFMA GEMM: A bf16 [M,K], Bt bf16 [N,K], 128x128 tile ----------------
// EPI: 0 none, 1 gelu, 2 sigmoid, 3 fused SSE-gate (Cb = padded bf16 image, needs gfac+res).
// HASRES: add res[M,N] f32 after EPI.  OUTF: write f32 Cf, OUTB: write bf16 Cb.
template<int EPI, bool HASRES, bool OUTF, bool OUTB>
__global__ __launch_bounds__(256) void mfma_gemm(
    const unsigned short* __restrict__ A, const unsigned short* __restrict__ Bt,
    const float* __restrict__ bias, const float* __restrict__ res,
    const float* __restrict__ gfac,
    float* __restrict__ Cf, unsigned short* __restrict__ Cb,
    int M, int N, int K)
{
    __shared__ __align__(16) unsigned short As[4096];
    __shared__ __align__(16) unsigned short Bs[4096];
    const int tid = threadIdx.x;
    const int wid = tid >> 6, lane = tid & 63;
    const int row0 = blockIdx.y << 7, col0 = blockIdx.x << 7;
    const int wm = wid >> 1, wn = wid & 1;
    const int li = lane & 15, qq = lane >> 4;

    f32x4 acc[4][4] = {};
    const int nk = K >> 5;
    for(int kt=0; kt<nk; kt++){
        const int k0 = kt << 5;
        #pragma unroll
        for(int i=0;i<2;i++){
            int boff = wid*2048 + i*1024 + (lane<<4);  // byte slot in tile
            int row = boff >> 6;
            int t = (boff >> 4) & 3;
            int q = t ^ ((row >> 1) & 3);
            gload_lds16(A  + (size_t)(row0+row)*K + k0 + q*8, (char*)As + wid*2048 + i*1024);
            gload_lds16(Bt + (size_t)(col0+row)*K + k0 + q*8, (char*)Bs + wid*2048 + i*1024);
        }
        __syncthreads();
        s16x8 af[4], bfr[4];
        #pragma unroll
        for(int mi=0;mi<4;mi++){
            int r = (wm<<6) + (mi<<4) + li;
            af[mi] = *(const s16x8*)((const char*)As + r*64 + ((qq ^ ((r>>1)&3))<<4));
        }
        #pragma unroll
        for(int nj=0;nj<4;nj++){
            int r = (wn<<6) + (nj<<4) + li;
            bfr[nj] = *(const s16x8*)((const char*)Bs + r*64 + ((qq ^ ((r>>1)&3))<<4));
        }
        #pragma unroll
        for(int mi=0;mi<4;mi++)
            #pragma unroll
            for(int nj=0;nj<4;nj++)
                acc[mi][nj] = __builtin_amdgcn_mfma_f32_16x16x32_bf16(af[mi], bfr[nj], acc[mi][nj], 0,0,0);
        __syncthreads();
    }
    #pragma unroll
    for(int mi=0;mi<4;mi++){
        #pragma unroll
        for(int nj=0;nj<4;nj++){
            int col = col0 + (wn<<6) + (nj<<4) + li;
            float bv = bias ? bias[col] : 0.0f;
            #pragma unroll
            for(int rr=0;rr<4;rr++){
                int row = row0 + (wm<<6) + (mi<<4) + (qq<<2) + rr;
                float v = acc[mi][nj][rr] + bv;
                if(EPI==1) v = gelu_f(v);
                if(EPI==2) v = sigmoid_f(v);
                if(EPI==3){
                    int n = row / 3136; int rem = row % 3136;
                    int h = rem / 56, w = rem % 56;
                    float xv = res[(size_t)row*N + col];
                    v = xv*(gfac[n*CC + col] + sigmoid_f(v));
                    size_t dst = ((size_t)(64 + n*3364 + (h+1)*58 + (w+1)))*CC + col;
                    Cb[dst] = f2bf(v);
                } else {
                    if(HASRES) v += res[(size_t)row*N + col];
                    if(OUTF) Cf[(size_t)row*N + col] = v;
                    if(OUTB) Cb[(size_t)row*N + col] = f2bf(v);
                }
            }
        }
    }
}

// ---------------- conv 3x3 as 9-tap accumulated MFMA GEMM over padded image ----------------
__global__ __launch_bounds__(256) void conv_gemm(
    const unsigned short* __restrict__ P, const unsigned short* __restrict__ CBt,
    const float* __restrict__ bias, float* __restrict__ out)
{
    __shared__ __align__(16) unsigned short As[4096];
    __shared__ __align__(16) unsigned short Bs[4096];
    const int tid = threadIdx.x;
    const int wid = tid >> 6, lane = tid & 63;
    const int row0 = blockIdx.y << 7, col0 = blockIdx.x << 7;
    const int wm = wid >> 1, wn = wid & 1;
    const int li = lane & 15, qq = lane >> 4;
    const int K = 256;

    f32x4 acc[4][4] = {};
    for(int tap=0; tap<9; tap++){
        int d = ((tap/3)-1)*58 + (tap%3) - 1;
        const unsigned short* A  = P + (size_t)(64 + d)*256;
        const unsigned short* Bt = CBt + (size_t)tap*65536;
        for(int kt=0; kt<8; kt++){
            const int k0 = kt << 5;
            #pragma unroll
            for(int i=0;i<2;i++){
                int boff = wid*2048 + i*1024 + (lane<<4);
                int row = boff >> 6;
                int t = (boff >> 4) & 3;
                int q = t ^ ((row >> 1) & 3);
                gload_lds16(A  + (size_t)(row0+row)*K + k0 + q*8, (char*)As + wid*2048 + i*1024);
                gload_lds16(Bt + (size_t)(col0+row)*K + k0 + q*8, (char*)Bs + wid*2048 + i*1024);
            }
            __syncthreads();
            s16x8 af[4], bfr[4];
            #pragma unroll
            for(int mi=0;mi<4;mi++){
                int r = (wm<<6) + (mi<<4) + li;
                af[mi] = *(const s16x8*)((const char*)As + r*64 + ((qq ^ ((r>>1)&3))<<4));
            }
            #pragma unroll
            for(int nj=0;nj<4;nj++){
                int r = (wn<<6) + (nj<<4) + li;
                bfr[nj] = *(const s16x8*)((const char*)Bs + r*64 + ((qq ^ ((r>>1)&3))<<4));
            }
            #pragma unroll
            for(int mi=0;mi<4;mi++)
                #pragma unroll
                for(int nj=0;nj<4;nj++)
                    acc[mi][nj] = __builtin_amdgcn_mfma_f32_16x16x32_bf16(af[mi], bfr[nj], acc[mi][nj], 0,0,0);
            __syncthreads();
        }
    }
    #pragma unroll
    for(int mi=0;mi<4;mi++){
        #pragma unroll
        for(int nj=0;nj<4;nj++){
            int col = col0 + (wn<<6) + (nj<<4) + li;
            float bv = bias[col];
            #pragma unroll
            for(int rr=0;rr<4;rr++){
                int prow = row0 + (wm<<6) + (mi<<4) + (qq<<2) + rr;
                if(prow < NB*3364){
                    int n = prow / 3364; int rem = prow % 3364;
                    int y = rem / 58, x = rem % 58;
                    if(y>=1 && y<57 && x>=1 && x<57){
                        out[(((size_t)n*CC + col)*HH + (y-1))*WW + (x-1)] = acc[mi][nj][rr] + bv;
                    }
                }
            }
        }
    }
}

// ---------------- region means of q and k (bf16 qkv) ----------------
__global__ __launch_bounds__(256) void winmean_kernel(const unsigned short* __restrict__ qkv,
                                                      float* __restrict__ qwin, float* __restrict__ kwin){
    int b = blockIdx.x;      // n*49 + p
    int n = b / P2, p = b % P2;
    int c = threadIdx.x;
    int hb = (p/7)*8, wb = (p%7)*8;
    float sq=0.f, sk=0.f;
    for(int pixi=0;pixi<64;pixi++){
        int h = hb + (pixi>>3), w = wb + (pixi&7);
        const unsigned short* row = &qkv[((size_t)(n*HH+h)*WW + w)*768];
        sq += bf2f(row[c]);
        sk += bf2f(row[256+c]);
    }
    qwin[(size_t)b*CC+c] = sq*(1.0f/64.0f);
    kwin[(size_t)b*CC+c] = sk*(1.0f/64.0f);
}

// ---------------- routing logits + top-4 ----------------
__global__ __launch_bounds__(64) void route_kernel(const float* __restrict__ qwin, const float* __restrict__ kwin,
                                                   int* __restrict__ idxout){
    int b = blockIdx.x;      // n*49 + p
    int n = b / P2;
    int j = threadIdx.x;
    __shared__ float lg[64];
    float v = -1e30f;
    if(j < P2){
        const float* q = &qwin[(size_t)b*CC];
        const float* k = &kwin[(size_t)(n*P2+j)*CC];
        float s=0.f;
        for(int c=0;c<CC;c++) s += q[c]*k[c];
        v = s*0.0625f;
    }
    lg[j] = v;
    __syncthreads();
    if(j==0){
        for(int t=0;t<TOPKN;t++){
            int best=0; float bv=lg[0];
            for(int u=1;u<P2;u++) if(lg[u]>bv){bv=lg[u];best=u;}
            idxout[b*TOPKN+t]=best;
            lg[best]=-1e30f;
        }
    }
}

// ---------------- MFMA flash attention: ONE WAVE per (n,p,head), bf16 qkv ----------------
// S^T = K*Q^T (raw), scaled by 1/16*log2e post-MFMA; softmax per query column;
// P^T round-trips 4KB swizzled LDS; O^T = V^T*P^T.
__global__ __launch_bounds__(64) void attn_kernel(const unsigned short* __restrict__ qkv,
                                                  const int* __restrict__ idx,
                                                  float* __restrict__ out){
    __shared__ __align__(16) unsigned short P_lds[64*32];   // [q][key] bf16, byte ^= (q&3)<<4
    __shared__ int pixo[256];                               // gathered global pixel index per key
    int b = blockIdx.x;
    int m = b & 7; int np = b >> 3;      // np = n*49+p
    int n = np / P2, p = np % P2;
    int lane = threadIdx.x;
    int li = lane & 15, g = lane >> 4;
    int hb = (p/7)*8, wb = (p%7)*8;

    #pragma unroll
    for(int t4=0;t4<4;t4++){
        int r = idx[np*TOPKN + t4];           // wave-uniform
        int pixi = lane;
        int h = (r/7)*8 + (pixi>>3), w = (r%7)*8 + (pixi&7);
        pixo[t4*64 + lane] = (n*HH+h)*WW + w;
    }
    __syncthreads();

    // Q fragments (B-operand of S^T): row=q=li+q4*16, k=ch=g*8+j — direct 16B loads
    s16x8 qfr[4];
    #pragma unroll
    for(int q4=0;q4<4;q4++){
        int q = q4*16 + li;
        int h = hb + (q>>3), w = wb + (q&7);
        qfr[q4] = *reinterpret_cast<const s16x8*>(&qkv[((size_t)(n*HH+h)*WW + w)*768 + m*32 + g*8]);
    }

    const float SC = 0.0625f * 1.44269504088896f;
    f32x4 ot[2][4] = {};                 // O^T frags [chf][qf]
    float mx[4], lsum[4];
    #pragma unroll
    for(int q4=0;q4<4;q4++){ mx[q4] = -3e38f; lsum[q4] = 0.0f; }

    for(int kb=0; kb<8; kb++){
        // ---- S^T tile (32 keys x 64 queries) ----
        f32x4 st[2][4] = {};
        #pragma unroll
        for(int kf=0;kf<2;kf++){
            int key = kb*32 + kf*16 + li;
            s16x8 kfrag = *reinterpret_cast<const s16x8*>(&qkv[(size_t)pixo[key]*768 + 256 + m*32 + g*8]);
            #pragma unroll
            for(int q4=0;q4<4;q4++)
                st[kf][q4] = __builtin_amdgcn_mfma_f32_16x16x32_bf16(kfrag, qfr[q4], st[kf][q4], 0,0,0);
        }
        #pragma unroll
        for(int kf=0;kf<2;kf++)
            #pragma unroll
            for(int q4=0;q4<4;q4++)
                #pragma unroll
                for(int r=0;r<4;r++) st[kf][q4][r] *= SC;
        // ---- online softmax per query column (q = li + q4*16) ----
        #pragma unroll
        for(int q4=0;q4<4;q4++){
            float pm = st[0][q4][0];
            #pragma unroll
            for(int r=1;r<4;r++) pm = fmaxf(pm, st[0][q4][r]);
            #pragma unroll
            for(int r=0;r<4;r++) pm = fmaxf(pm, st[1][q4][r]);
            pm = fmaxf(pm, __shfl_xor(pm, 16));
            pm = fmaxf(pm, __shfl_xor(pm, 32));
            float mnew = fmaxf(mx[q4], pm);
            float fsc = exp2f(mx[q4] - mnew);
            mx[q4] = mnew;
            float ps = 0.0f;
            #pragma unroll
            for(int kf=0;kf<2;kf++)
                #pragma unroll
                for(int r=0;r<4;r++){
                    float pv = exp2f(st[kf][q4][r] - mnew);
                    st[kf][q4][r] = pv;
                    ps += pv;
                }
            ps += __shfl_xor(ps, 16);
            ps += __shfl_xor(ps, 32);
            lsum[q4] = lsum[q4]*fsc + ps;
            #pragma unroll
            for(int chf=0;chf<2;chf++)
                #pragma unroll
                for(int r=0;r<4;r++) ot[chf][q4][r] *= fsc;
        }
        // ---- write P^T to LDS ----
        #pragma unroll
        for(int q4=0;q4<4;q4++){
            int q = q4*16 + li;
            #pragma unroll
            for(int kf=0;kf<2;kf++){
                unsigned lo = ((unsigned)f2bf(st[kf][q4][0])) | (((unsigned)f2bf(st[kf][q4][1]))<<16);
                unsigned hi = ((unsigned)f2bf(st[kf][q4][2])) | (((unsigned)f2bf(st[kf][q4][3]))<<16);
                int byte = (q*64 + kf*32 + g*8) ^ ((q&3)<<4);
                *reinterpret_cast<uint2*>((char*)P_lds + byte) = make_uint2(lo, hi);
            }
        }
        __syncthreads();
        // ---- read P^T back as B-frags ----
        s16x8 pfr[4];
        #pragma unroll
        for(int q4=0;q4<4;q4++){
            int q = q4*16 + li;
            int byte = (q*64 + g*16) ^ ((q&3)<<4);
            pfr[q4] = *reinterpret_cast<const s16x8*>((const char*)P_lds + byte);
        }
        // ---- O^T += V^T * P^T ----
        #pragma unroll
        for(int chf=0;chf<2;chf++){
            s16x8 vfr;
            #pragma unroll
            for(int j=0;j<8;j++){
                int key = kb*32 + g*8 + j;
                vfr[j] = (short)qkv[(size_t)pixo[key]*768 + 512 + m*32 + chf*16 + li];
            }
            #pragma unroll
            for(int q4=0;q4<4;q4++)
                ot[chf][q4] = __builtin_amdgcn_mfma_f32_16x16x32_bf16(vfr, pfr[q4], ot[chf][q4], 0,0,0);
        }
        __syncthreads();
    }
    // ---- epilogue ----
    #pragma unroll
    for(int q4=0;q4<4;q4++){
        int q = q4*16 + li;
        int h = hb + (q>>3), w = wb + (q&7);
        float inv = 1.0f / lsum[q4];
        float* orow = &out[((size_t)(n*HH+h)*WW + w)*CC + m*32];
        #pragma unroll
        for(int chf=0;chf<2;chf++)
            #pragma unroll
            for(int r=0;r<4;r++)
                orow[chf*16 + g*4 + r] = ot[chf][q4][r]*inv;
    }
}

// ---------------- LEPE tiled: attn_out(f32) + dwconv5(v bf16) -> bf16 ----------------
__global__ __launch_bounds__(256) void lepe_kernel(const unsigned short* __restrict__ qkv,
                                                   const float* __restrict__ attn,
                                                   const float* __restrict__ lw, const float* __restrict__ lb,
                                                   unsigned short* __restrict__ outb){
    __shared__ float tile[144][64];     // 12x12 spatial halo x 64 channels
    int tileid = blockIdx.x;            // 0..48
    int cg = blockIdx.y;                // 0..3
    int n = blockIdx.z;
    int hb = (tileid/7)*8, wb = (tileid%7)*8;
    int tid = threadIdx.x;
    for(int ii=tid; ii<144*64; ii+=256){
        int sp = ii >> 6, cl = ii & 63;
        int ty = sp / 12, tx = sp % 12;
        int y = hb + ty - 2, x = wb + tx - 2;
        float v = 0.0f;
        if(y>=0 && y<HH && x>=0 && x<WW)
            v = bf2f(qkv[((size_t)(n*HH+y)*WW + x)*768 + 512 + cg*64 + cl]);
        tile[sp][cl] = v;
    }
    __syncthreads();
    int cl = tid & 63;
    int c = cg*64 + cl;
    float wv[25];
    #pragma unroll
    for(int t=0;t<25;t++) wv[t] = lw[c*25 + t];
    float bias = lb[c];
    for(int oi = tid; oi < 4096; oi += 256){
        int sp = oi >> 6;
        int py = sp >> 3, px = sp & 7;
        float a = bias;
        #pragma unroll
        for(int dy=0;dy<5;dy++)
            #pragma unroll
            for(int dx=0;dx<5;dx++)
                a += tile[(py+dy)*12 + px+dx][cl]*wv[dy*5+dx];
        size_t pix = (size_t)(n*HH + hb+py)*WW + wb+px;
        outb[pix*CC + c] = f2bf(attn[pix*CC + c] + a);
    }
}

// ---------------- global average pool: 392 blocks, atomic accumulate of mean ----------------
__global__ __launch_bounds__(256) void pool_kernel(const float* __restrict__ x, float* __restrict__ pooled){
    int n = blockIdx.y, c = threadIdx.x;
    int p0 = blockIdx.x*64;
    float s=0.f;
    for(int pp=0;pp<64;pp++) s += x[((size_t)n*3136 + p0 + pp)*CC + c];
    atomicAdd(&pooled[n*CC+c], s*(1.0f/3136.0f));
}

// ---------------- channel SE (two tiny FCs) ----------------
__global__ __launch_bounds__(256) void cse_kernel(const float* __restrict__ pooled,
                                                  const float* __restrict__ w1, const float* __restrict__ b1,
                                                  const float* __restrict__ w2, const float* __restrict__ b2,
                                                  float* __restrict__ cfac){
    int n = blockIdx.x, t = threadIdx.x;
    __shared__ float c1[16];
    if(t < 16){
        float s = b1[t];
        for(int c=0;c<CC;c++) s += pooled[n*CC+c]*w1[t*CC+c];
        c1[t] = fmaxf(s, 0.0f);
    }
    __syncthreads();
    float s = b2[t];
    #pragma unroll
    for(int j=0;j<16;j++) s += c1[j]*w2[t*16+j];
    cfac[n*CC+t] = sigmoid_f(s);
}

extern "C" void kernel_launch(void* const* d_in, const int* in_sizes, int n_in,
                              void* d_out, int out_size, void* d_ws, size_t ws_size,
                              hipStream_t stream){
    const float* x_in   = (const float*)d_in[0];
    const float* ln1w   = (const float*)d_in[1];
    const float* ln1b   = (const float*)d_in[2];
    const float* qkvw   = (const float*)d_in[3];
    const float* qkvb   = (const float*)d_in[4];
    const float* lepew  = (const float*)d_in[5];
    const float* lepeb  = (const float*)d_in[6];
    const float* wow    = (const float*)d_in[7];
    const float* wob    = (const float*)d_in[8];
    const float* ln2w   = (const float*)d_in[9];
    const float* ln2b   = (const float*)d_in[10];
    const float* mlp1w  = (const float*)d_in[11];
    const float* mlp1b  = (const float*)d_in[12];
    const float* mlp2w  = (const float*)d_in[13];
    const float* mlp2b  = (const float*)d_in[14];
    const float* cse1w  = (const float*)d_in[15];
    const float* cse1b  = (const float*)d_in[16];
    const float* cse2w  = (const float*)d_in[17];
    const float* cse2b  = (const float*)d_in[18];
    const float* ssew   = (const float*)d_in[19];
    const float* sseb   = (const float*)d_in[20];
    const float* convw  = (const float*)d_in[21];
    const float* convb  = (const float*)d_in[22];
    float* out = (float*)d_out;

    char* base = (char*)d_ws;
    float* bufx   = (float*)base;                         base += (size_t)PIX*CC*4;
    float* buftmp = (float*)base;                         base += (size_t)PIX*CC*4;
    // big region: holds qkv bf16 [PIX,768] OR hid bf16 [PIX,1024] OR Ppad [27136,256] bf16
    unsigned short* qkvB = (unsigned short*)base;
    unsigned short* hid  = (unsigned short*)base;
    unsigned short* Ppad = (unsigned short*)base;         base += (size_t)PIX*1024*2;
    float* qwin   = (float*)base;                         base += (size_t)NB*P2*CC*4;
    float* kwin   = (float*)base;                         base += (size_t)NB*P2*CC*4;
    float* pooled = (float*)base;                         base += NB*CC*4;
    float* cfac   = (float*)base;                         base += NB*CC*4;
    int*   idxb   = (int*)base;                           base += 2048*4;
    unsigned short* bufxn = (unsigned short*)base;        base += (size_t)PIX*CC*2;
    unsigned short* qkvbt = (unsigned short*)base;        base += (size_t)4*768*256*2;
    unsigned short* wobt  = (unsigned short*)base;        base += (size_t)4*256*256*2;
    unsigned short* m1bt  = (unsigned short*)base;        base += (size_t)4*1024*256*2;
    unsigned short* m2bt  = (unsigned short*)base;        base += (size_t)4*256*1024*2;
    unsigned short* ssebt = (unsigned short*)base;        base += (size_t)256*256*2;
    unsigned short* cvbt  = (unsigned short*)base;        base += (size_t)9*256*256*2;

    // ---- weight prep (bf16, transposed to [N,K]) ----
    wtrans<<<dim3(24, 8, 4), dim3(32,32), 0, stream>>>(qkvw, qkvbt, 256, 768);
    wtrans<<<dim3(8, 8, 4),  dim3(32,32), 0, stream>>>(wow,  wobt,  256, 256);
    wtrans<<<dim3(32, 8, 4), dim3(32,32), 0, stream>>>(mlp1w, m1bt, 256, 1024);
    wtrans<<<dim3(8, 32, 4), dim3(32,32), 0, stream>>>(mlp2w, m2bt, 1024, 256);
    tobf16<<<256, 256, 0, stream>>>(ssew, ssebt, 65536);
    convw_reorder<<<2304, 256, 0, stream>>>(convw, cvbt);

    nchw_to_nhwc<<<dim3(NB*98, 8), dim3(32,32), 0, stream>>>(x_in, bufx);

    for(int i=0;i<4;i++){
        ln_bf16<<<PIX/4,256,0,stream>>>(bufx, ln1w+i*CC, ln1b+i*CC, bufxn);
        mfma_gemm<0,false,false,true><<<dim3(6,196),256,0,stream>>>(
            bufxn, qkvbt+(size_t)i*768*256, qkvb+i*768, nullptr, nullptr, nullptr, qkvB, PIX, 768, 256);
        winmean_kernel<<<NB*P2,256,0,stream>>>(qkvB, qwin, kwin);
        route_kernel<<<NB*P2,64,0,stream>>>(qwin, kwin, idxb);
        attn_kernel<<<NB*P2*8,64,0,stream>>>(qkvB, idxb, buftmp);
        lepe_kernel<<<dim3(49,4,NB),256,0,stream>>>(qkvB, buftmp, lepew+(size_t)i*CC*25, lepeb+i*CC, bufxn);
        mfma_gemm<0,true,true,false><<<dim3(2,196),256,0,stream>>>(
            bufxn, wobt+(size_t)i*256*256, wob+i*CC, bufx, nullptr, bufx, nullptr, PIX, 256, 256);
        ln_bf16<<<PIX/4,256,0,stream>>>(bufx, ln2w+i*CC, ln2b+i*CC, bufxn);
        mfma_gemm<1,false,false,true><<<dim3(8,196),256,0,stream>>>(
            bufxn, m1bt+(size_t)i*1024*256, mlp1b+i*1024, nullptr, nullptr, nullptr, hid, PIX, 1024, 256);
        mfma_gemm<0,true,true,false><<<dim3(2,196),256,0,stream>>>(
            hid, m2bt+(size_t)i*256*1024, mlp2b+i*CC, bufx, nullptr, bufx, nullptr, PIX, 256, 1024);
    }

    hipMemsetAsync(pooled, 0, NB*CC*sizeof(float), stream);
    pool_kernel<<<dim3(49,NB),256,0,stream>>>(bufx, pooled);
    cse_kernel<<<NB,256,0,stream>>>(pooled, cse1w, cse1b, cse2w, cse2b, cfac);
    tobf16<<<PIX,256,0,stream>>>(bufx, bufxn, PIX*CC);
    hipMemsetAsync(Ppad, 0, (size_t)27136*256*2, stream);
    mfma_gemm<3,false,false,false><<<dim3(2,196),256,0,stream>>>(
        bufxn, ssebt, sseb, bufx, cfac, nullptr, Ppad, PIX, 256, 256);
    conv_gemm<<<dim3(2,211),256,0,stream>>>(Ppad, cvbt, convb, out);
}